// Round 2
// baseline (6184.085 us; speedup 1.0000x reference)
//
#include <hip/hip_runtime.h>
#include <hip/hip_bf16.h>
#include <cstdio>

// ---------------------------------------------------------------------------
// RWKV6 TimeMix: B=4, T=2048, C=2048, H=32, N=64, DMIX=32, DDEC=64
// ---------------------------------------------------------------------------

typedef __attribute__((ext_vector_type(8))) short bf16x8;    // 8 bf16 = 4 VGPRs
typedef __attribute__((ext_vector_type(4))) float floatx4;

#define T_DIM 2048
#define C_DIM 2048
#define B_DIM 4
#define M_ROWS (B_DIM * T_DIM)   // 8192

// ---------------- global_load_lds helper (16B per lane) --------------------
typedef const unsigned int __attribute__((address_space(1)))* gas1_t;
typedef unsigned int __attribute__((address_space(3)))* las3_t;
__device__ __forceinline__ void gl_lds16(const void* g, void* l) {
    __builtin_amdgcn_global_load_lds((gas1_t)g, (las3_t)l, 16, 0, 0);
}

__device__ __forceinline__ float bflo(unsigned u) {
    return __uint_as_float(u << 16);
}
__device__ __forceinline__ float bfhi(unsigned u) {
    return __uint_as_float(u & 0xffff0000u);
}

// ---------------- transpose + cast + zero-pad ------------------------------
// in: [R][Cin] fp32  ->  out: [Cout][R]  (bf16 or fp32); cols >= Cin get 0.
// grid: (Cout/32, R/32)
__global__ __launch_bounds__(256) void k_transpose(
    const float* __restrict__ in, void* __restrict__ out,
    int R, int Cin, int to_bf16)
{
    __shared__ float tile[32][33];
    const int tx = threadIdx.x & 31, ty = threadIdx.x >> 5;
    const int cbase = blockIdx.x * 32, rbase = blockIdx.y * 32;
#pragma unroll
    for (int i = 0; i < 4; i++) {
        int r = rbase + ty + i * 8;
        int c = cbase + tx;
        tile[ty + i * 8][tx] = (c < Cin) ? in[(size_t)r * Cin + c] : 0.0f;
    }
    __syncthreads();
    if (to_bf16) {
        __hip_bfloat16* ob = (__hip_bfloat16*)out;
#pragma unroll
        for (int i = 0; i < 4; i++) {
            int c = cbase + ty + i * 8;
            ob[(size_t)c * R + rbase + tx] = __float2bfloat16(tile[tx][ty + i * 8]);
        }
    } else {
        float* of = (float*)out;
#pragma unroll
        for (int i = 0; i < 4; i++) {
            int c = cbase + ty + i * 8;
            of[(size_t)c * R + rbase + tx] = tile[tx][ty + i * 8];
        }
    }
}

// ---------------- XX = bf16(x + (prev-x)*tmx); also x_last ------------------
__global__ __launch_bounds__(256) void k_xx(
    const float* __restrict__ x, const float* __restrict__ shift,
    const float* __restrict__ tmx,
    __hip_bfloat16* __restrict__ XX, float* __restrict__ xlast)
{
    const int row = blockIdx.x;
    const int b = row >> 11, t = row & 2047;
    const int c0 = threadIdx.x * 8;
    const float* xrow = x + (size_t)row * C_DIM;
    const float* prow = (t == 0) ? (shift + (size_t)b * C_DIM) : (xrow - C_DIM);
    float4 xa = ((const float4*)(xrow + c0))[0];
    float4 xb = ((const float4*)(xrow + c0))[1];
    float4 pa = ((const float4*)(prow + c0))[0];
    float4 pb = ((const float4*)(prow + c0))[1];
    float xv8[8] = {xa.x, xa.y, xa.z, xa.w, xb.x, xb.y, xb.z, xb.w};
    float pv8[8] = {pa.x, pa.y, pa.z, pa.w, pb.x, pb.y, pb.z, pb.w};
    union { bf16x8 v8; __hip_bfloat16 e[8]; } u;
#pragma unroll
    for (int j = 0; j < 8; j++)
        u.e[j] = __float2bfloat16(fmaf(pv8[j] - xv8[j], tmx[c0 + j], xv8[j]));
    *(bf16x8*)(XX + (size_t)row * C_DIM + c0) = u.v8;
    if (t == T_DIM - 1) {
        ((float4*)(xlast + (size_t)b * C_DIM + c0))[0] = xa;
        ((float4*)(xlast + (size_t)b * C_DIM + c0))[1] = xb;
    }
}

// ---------------- H = tanh(XX @ w1) : M=8192, N=256(padded), K=2048 ---------
// tile M=64,N=256,BK=32; 4 waves, wave w = m-frag w, 16 n-frags. grid 128.
__global__ __launch_bounds__(256) void k_gemm_h(
    const __hip_bfloat16* __restrict__ A,   // XX [8192][2048]
    const __hip_bfloat16* __restrict__ Bt,  // w1tb [256][2048]
    float* __restrict__ Hout)               // [8192][256]
{
    __shared__ __hip_bfloat16 As[64 * 32];
    __shared__ __hip_bfloat16 Bs[256 * 32];
    const int tid = threadIdx.x;
    const int m0 = blockIdx.x * 64;
    const int wave = tid >> 6, lane = tid & 63;
    const int fcol = lane & 15, quad = lane >> 4;
    floatx4 acc[16];
#pragma unroll
    for (int i = 0; i < 16; i++) acc[i] = (floatx4){0.f, 0.f, 0.f, 0.f};

    const int rA = tid >> 2, kcA = (tid & 3) * 8;
    const __hip_bfloat16* gA = A + (size_t)(m0 + rA) * 2048 + kcA;
    __hip_bfloat16* lA = As + tid * 8;
    const __hip_bfloat16* gB[4];
    __hip_bfloat16* lB[4];
#pragma unroll
    for (int s = 0; s < 4; s++) {
        int q = tid + 256 * s;
        gB[s] = Bt + (size_t)(q >> 2) * 2048 + (q & 3) * 8;
        lB[s] = Bs + q * 8;
    }
    for (int kk = 0; kk < 2048; kk += 32) {
        gl_lds16(gA + kk, lA);
#pragma unroll
        for (int s = 0; s < 4; s++) gl_lds16(gB[s] + kk, lB[s]);
        __syncthreads();
        bf16x8 aF = *(const bf16x8*)(As + (wave * 16 + fcol) * 32 + quad * 8);
#pragma unroll
        for (int ni = 0; ni < 16; ni++) {
            bf16x8 bF = *(const bf16x8*)(Bs + (ni * 16 + fcol) * 32 + quad * 8);
            acc[ni] = __builtin_amdgcn_mfma_f32_16x16x32_bf16(aF, bF, acc[ni], 0, 0, 0);
        }
        __syncthreads();
    }
#pragma unroll
    for (int ni = 0; ni < 16; ni++) {
        int col = ni * 16 + fcol;
#pragma unroll
        for (int g = 0; g < 4; g++) {
            int row = m0 + wave * 16 + quad * 4 + g;
            Hout[(size_t)row * 256 + col] = tanhf(acc[ni][g]);
        }
    }
}

// ---------------- G = tanh(A @ Bt^T) : N=64, K=2048 -------------------------
// tile M=64,N=64,BK=32; wave w = m-frag w, 4 n-frags. grid 128. out bf16.
__global__ __launch_bounds__(256) void k_gemm_n64(
    const __hip_bfloat16* __restrict__ A,   // [8192][2048]
    const __hip_bfloat16* __restrict__ Bt,  // [64][2048]
    __hip_bfloat16* __restrict__ G)         // [8192][64]
{
    __shared__ __hip_bfloat16 As[64 * 32];
    __shared__ __hip_bfloat16 Bs[64 * 32];
    const int tid = threadIdx.x;
    const int m0 = blockIdx.x * 64;
    const int wave = tid >> 6, lane = tid & 63;
    const int fcol = lane & 15, quad = lane >> 4;
    floatx4 acc[4];
#pragma unroll
    for (int i = 0; i < 4; i++) acc[i] = (floatx4){0.f, 0.f, 0.f, 0.f};

    const int r = tid >> 2, kc = (tid & 3) * 8;
    const __hip_bfloat16* gA = A + (size_t)(m0 + r) * 2048 + kc;
    const __hip_bfloat16* gB = Bt + (size_t)r * 2048 + kc;
    __hip_bfloat16* lA = As + tid * 8;
    __hip_bfloat16* lB = Bs + tid * 8;
    for (int kk = 0; kk < 2048; kk += 32) {
        gl_lds16(gA + kk, lA);
        gl_lds16(gB + kk, lB);
        __syncthreads();
        bf16x8 aF = *(const bf16x8*)(As + (wave * 16 + fcol) * 32 + quad * 8);
#pragma unroll
        for (int ni = 0; ni < 4; ni++) {
            bf16x8 bF = *(const bf16x8*)(Bs + (ni * 16 + fcol) * 32 + quad * 8);
            acc[ni] = __builtin_amdgcn_mfma_f32_16x16x32_bf16(aF, bF, acc[ni], 0, 0, 0);
        }
        __syncthreads();
    }
#pragma unroll
    for (int ni = 0; ni < 4; ni++) {
        int col = ni * 16 + fcol;
#pragma unroll
        for (int g = 0; g < 4; g++) {
            int row = m0 + wave * 16 + quad * 4 + g;
            G[(size_t)row * 64 + col] = __float2bfloat16(tanhf(acc[ni][g]));
        }
    }
}

// ---------------- mix-apply: xout_f = x + dx*(maa_f + H_f @ w2_f) -----------
// 16 rows/block (amortizes w2 reads x16). grid 512.
__global__ __launch_bounds__(256) void k_mixapply(
    const float* __restrict__ x, const float* __restrict__ shift,
    const float* __restrict__ H, const float* __restrict__ w2,
    const float* __restrict__ tmr, const float* __restrict__ tmk,
    const float* __restrict__ tmv, const float* __restrict__ tmw,
    const float* __restrict__ tmv2,
    __hip_bfloat16* __restrict__ xr, __hip_bfloat16* __restrict__ xk,
    __hip_bfloat16* __restrict__ xv, __hip_bfloat16* __restrict__ xw,
    __hip_bfloat16* __restrict__ xv2)
{
    __shared__ float hsm[16][160];
    const int row0 = blockIdx.x * 16;
    const int b = row0 >> 11;
    const int tid = threadIdx.x;
    for (int idx = tid; idx < 16 * 160; idx += 256)
        hsm[idx / 160][idx % 160] = H[(size_t)(row0 + idx / 160) * 256 + idx % 160];
    __syncthreads();
    const int c0 = tid * 8;
    const float* maas[5] = {tmr, tmk, tmv, tmw, tmv2};
    __hip_bfloat16* outs[5] = {xr, xk, xv, xw, xv2};
    for (int rc = 0; rc < 16; rc += 8) {
#pragma unroll
        for (int f = 0; f < 5; f++) {
            float acc[8][8];
#pragma unroll
            for (int r = 0; r < 8; r++)
#pragma unroll
                for (int j = 0; j < 8; j++) acc[r][j] = 0.f;
#pragma unroll 4
            for (int d = 0; d < 32; d++) {
                const float4* wp = (const float4*)(w2 + (size_t)(f * 32 + d) * 2048 + c0);
                float4 p0 = wp[0], p1 = wp[1];
                float wv[8] = {p0.x, p0.y, p0.z, p0.w, p1.x, p1.y, p1.z, p1.w};
#pragma unroll
                for (int r = 0; r < 8; r++) {
                    float h = hsm[rc + r][f * 32 + d];
#pragma unroll
                    for (int j = 0; j < 8; j++) acc[r][j] = fmaf(h, wv[j], acc[r][j]);
                }
            }
            const float* maa = maas[f];
            float m8[8];
#pragma unroll
            for (int j = 0; j < 8; j++) m8[j] = maa[c0 + j];
#pragma unroll
            for (int r = 0; r < 8; r++) {
                int row = row0 + rc + r;
                int t = row & 2047;
                const float* xrow = x + (size_t)row * C_DIM;
                const float* prow = (t == 0) ? (shift + (size_t)b * C_DIM) : (xrow - C_DIM);
                float4 xa = ((const float4*)(xrow + c0))[0];
                float4 xb = ((const float4*)(xrow + c0))[1];
                float4 pa = ((const float4*)(prow + c0))[0];
                float4 pb = ((const float4*)(prow + c0))[1];
                float xv8[8] = {xa.x, xa.y, xa.z, xa.w, xb.x, xb.y, xb.z, xb.w};
                float pv8[8] = {pa.x, pa.y, pa.z, pa.w, pb.x, pb.y, pb.z, pb.w};
                union { bf16x8 v8; __hip_bfloat16 e[8]; } u;
#pragma unroll
                for (int j = 0; j < 8; j++) {
                    float dx = pv8[j] - xv8[j];
                    u.e[j] = __float2bfloat16(fmaf(dx, m8[j] + acc[r][j], xv8[j]));
                }
                *(bf16x8*)(outs[f] + (size_t)row * C_DIM + c0) = u.v8;
            }
        }
    }
}

// ---------------- generic MFMA GEMM: M=8192, N=2048, K param ---------------
// C = A[M][K] @ Bt[N][K]^T, tile 128x128, BK=32, grid (16,64).
// mode 0: outF = val            mode 1: outB = bf16(val)
// mode 2: outB = bf16(val*(1-aux[idx]))   (k * (1-decay))
// mode 3: outF = exp(-exp(val + aux[col]))  (decay)
// mode 4: outB += val (bf16 rmw)            (v2 += lora)
__global__ __launch_bounds__(256) void k_gemm(
    const __hip_bfloat16* __restrict__ A,
    const __hip_bfloat16* __restrict__ Bt,
    int K, int mode,
    float* __restrict__ outF, __hip_bfloat16* __restrict__ outB,
    const float* __restrict__ aux)
{
    __shared__ __hip_bfloat16 As[128 * 32];
    __shared__ __hip_bfloat16 Bs[128 * 32];
    const int tid = threadIdx.x;
    const int m0 = blockIdx.y * 128, n0 = blockIdx.x * 128;
    const int wave = tid >> 6, lane = tid & 63;
    const int wm = (wave >> 1) * 64, wn = (wave & 1) * 64;
    const int fcol = lane & 15, quad = lane >> 4;

    floatx4 acc[4][4];
#pragma unroll
    for (int mi = 0; mi < 4; mi++)
#pragma unroll
        for (int ni = 0; ni < 4; ni++)
            acc[mi][ni] = (floatx4){0.f, 0.f, 0.f, 0.f};

    const int q0 = tid, q1 = tid + 256;
    const int r0 = q0 >> 2, kc0 = (q0 & 3) * 8;
    const int r1 = q1 >> 2, kc1 = (q1 & 3) * 8;
    const __hip_bfloat16* gA0 = A + (size_t)(m0 + r0) * K + kc0;
    const __hip_bfloat16* gA1 = A + (size_t)(m0 + r1) * K + kc1;
    const __hip_bfloat16* gB0 = Bt + (size_t)(n0 + r0) * K + kc0;
    const __hip_bfloat16* gB1 = Bt + (size_t)(n0 + r1) * K + kc1;
    __hip_bfloat16* lA0 = As + q0 * 8; __hip_bfloat16* lA1 = As + q1 * 8;
    __hip_bfloat16* lB0 = Bs + q0 * 8; __hip_bfloat16* lB1 = Bs + q1 * 8;

    for (int kk = 0; kk < K; kk += 32) {
        gl_lds16(gA0 + kk, lA0);
        gl_lds16(gA1 + kk, lA1);
        gl_lds16(gB0 + kk, lB0);
        gl_lds16(gB1 + kk, lB1);
        __syncthreads();
        bf16x8 aF[4], bF[4];
#pragma unroll
        for (int mi = 0; mi < 4; mi++)
            aF[mi] = *(const bf16x8*)(As + (wm + mi * 16 + fcol) * 32 + quad * 8);
#pragma unroll
        for (int ni = 0; ni < 4; ni++)
            bF[ni] = *(const bf16x8*)(Bs + (wn + ni * 16 + fcol) * 32 + quad * 8);
#pragma unroll
        for (int mi = 0; mi < 4; mi++)
#pragma unroll
            for (int ni = 0; ni < 4; ni++)
                acc[mi][ni] = __builtin_amdgcn_mfma_f32_16x16x32_bf16(
                    aF[mi], bF[ni], acc[mi][ni], 0, 0, 0);
        __syncthreads();
    }
    // C/D layout: col=lane&15, row=quad*4+reg  [m89/m91 verified]
#pragma unroll
    for (int mi = 0; mi < 4; mi++) {
#pragma unroll
        for (int ni = 0; ni < 4; ni++) {
            int rbase = m0 + wm + mi * 16 + quad * 4;
            int ccol = n0 + wn + ni * 16 + fcol;
#pragma unroll
            for (int g = 0; g < 4; g++) {
                size_t idx = (size_t)(rbase + g) * 2048 + ccol;
                float val = acc[mi][ni][g];
                if (mode == 0) {
                    outF[idx] = val;
                } else if (mode == 1) {
                    outB[idx] = __float2bfloat16(val);
                } else if (mode == 2) {
                    outB[idx] = __float2bfloat16(val * (1.0f - aux[idx]));
                } else if (mode == 3) {
                    outF[idx] = expf(-expf(val + aux[ccol]));
                } else {
                    outB[idx] = __float2bfloat16(__bfloat162float(outB[idx]) + val);
                }
            }
        }
    }
}

// ---------------- sequential WKV scan ---------------------------------------
// 128 blocks (b*H+h) x 64 threads (j = v-dim). r/k~/v bf16, decay fp32.
// y buffer holds v2 on entry; y[t] = r.state + v2 written in-place (bf16).
__global__ __launch_bounds__(64) void k_scan(
    const __hip_bfloat16* __restrict__ r, const __hip_bfloat16* __restrict__ k,
    const __hip_bfloat16* __restrict__ v, const float* __restrict__ dec,
    const float* __restrict__ state_in,
    __hip_bfloat16* __restrict__ y, float* __restrict__ state_out)
{
    const int bh = blockIdx.x;
    const int b = bh >> 5, h = bh & 31;
    const int j = threadIdx.x;
    float st[64];
    {
        const float* si = state_in + (size_t)bh * 4096 + j;
#pragma unroll
        for (int i = 0; i < 64; i++) st[i] = si[i * 64];
    }
    size_t base = (size_t)b * T_DIM * C_DIM + (size_t)h * 64;
    for (int t = 0; t < T_DIM; t++, base += C_DIM) {
        const float vj = __bfloat162float(v[base + j]);
        const uint4* rq = (const uint4*)(r + base);
        const uint4* kq = (const uint4*)(k + base);
        const float4* dq = (const float4*)(dec + base);
        float ya[4] = {0.f, 0.f, 0.f, 0.f};
#pragma unroll
        for (int c8 = 0; c8 < 8; c8++) {
            uint4 ru = rq[c8], ku = kq[c8];
            float4 d0 = dq[2 * c8], d1 = dq[2 * c8 + 1];
            float dd[8] = {d0.x, d0.y, d0.z, d0.w, d1.x, d1.y, d1.z, d1.w};
            unsigned ra[4] = {ru.x, ru.y, ru.z, ru.w};
            unsigned ka[4] = {ku.x, ku.y, ku.z, ku.w};
#pragma unroll
            for (int p = 0; p < 4; p++) {
                int i = c8 * 8 + 2 * p;
                float rl = bflo(ra[p]), rh = bfhi(ra[p]);
                float kl = bflo(ka[p]), kh = bfhi(ka[p]);
                ya[p] = fmaf(rl, st[i], ya[p]);
                st[i] = fmaf(st[i], dd[2 * p], kl * vj);
                ya[p] = fmaf(rh, st[i + 1], ya[p]);
                st[i + 1] = fmaf(st[i + 1], dd[2 * p + 1], kh * vj);
            }
        }
        float yout = (ya[0] + ya[1]) + (ya[2] + ya[3])
                   + __bfloat162float(y[base + j]);   // + v2
        y[base + j] = __float2bfloat16(yout);
    }
    float* so = state_out + (size_t)bh * 4096 + j;
#pragma unroll
    for (int i = 0; i < 64; i++) so[i * 64] = st[i];
}

// ---------------- in-place LayerNorm on bf16 rows ---------------------------
__global__ __launch_bounds__(256) void k_addln(
    __hip_bfloat16* __restrict__ y,
    const float* __restrict__ lnw, const float* __restrict__ lnb)
{
    __shared__ float ls[4], ls2[4];
    const int row = blockIdx.x;
    const size_t base = (size_t)row * C_DIM;
    const int tid = threadIdx.x;
    const int c0 = tid * 8;
    union { bf16x8 v8; __hip_bfloat16 e[8]; } uin;
    uin.v8 = *(const bf16x8*)(y + base + c0);
    float vbuf[8];
#pragma unroll
    for (int j = 0; j < 8; j++) vbuf[j] = __bfloat162float(uin.e[j]);
    float s = 0.f, s2 = 0.f;
#pragma unroll
    for (int j = 0; j < 8; j++) { s += vbuf[j]; s2 += vbuf[j] * vbuf[j]; }
#pragma unroll
    for (int off = 32; off > 0; off >>= 1) {
        s += __shfl_down(s, off, 64);
        s2 += __shfl_down(s2, off, 64);
    }
    const int w = tid >> 6;
    if ((tid & 63) == 0) { ls[w] = s; ls2[w] = s2; }
    __syncthreads();
    float S = ls[0] + ls[1] + ls[2] + ls[3];
    float S2 = ls2[0] + ls2[1] + ls2[2] + ls2[3];
    float mu = S * (1.0f / C_DIM);
    float var = S2 * (1.0f / C_DIM) - mu * mu;
    float rs = rsqrtf(var + 1e-5f);
    union { bf16x8 v8; __hip_bfloat16 e[8]; } u;
#pragma unroll
    for (int j = 0; j < 8; j++) {
        int c = c0 + j;
        u.e[j] = __float2bfloat16((vbuf[j] - mu) * rs * lnw[c] + lnb[c]);
    }
    *(bf16x8*)(y + base + c0) = u.v8;
}

// ---------------------------------------------------------------------------
extern "C" void kernel_launch(void* const* d_in, const int* in_sizes, int n_in,
                              void* d_out, int out_size, void* d_ws, size_t ws_size,
                              hipStream_t stream)
{
    const float* x     = (const float*)d_in[0];
    const float* shift = (const float*)d_in[1];
    const float* wkvin = (const float*)d_in[2];
    const float* tmx   = (const float*)d_in[3];
    const float* tmr   = (const float*)d_in[4];
    const float* tmk   = (const float*)d_in[5];
    const float* tmv   = (const float*)d_in[6];
    const float* tmw   = (const float*)d_in[7];
    const float* tmv2  = (const float*)d_in[8];
    const float* w1    = (const float*)d_in[9];    // [2048][160]
    const float* w2    = (const float*)d_in[10];   // [5][32][2048]
    const float* tdec  = (const float*)d_in[11];
    const float* dw1   = (const float*)d_in[12];   // [2048][64]
    const float* dw2   = (const float*)d_in[13];   // [64][2048]
    const float* vw1   = (const float*)d_in[14];
    const float* vw2   = (const float*)d_in[15];
    const float* Wr    = (const float*)d_in[16];
    const float* Wk    = (const float*)d_in[17];
    const float* Wv    = (const float*)d_in[18];
    const float* Wo    = (const float*)d_in[19];
    const float* lnw   = (const float*)d_in[20];
    const float* lnb   = (const float*)d_in[21];

    // ---- workspace layout (272.6 MB; buffers recycled across phases) ----
    const size_t SZ_XBF = (size_t)M_ROWS * C_DIM * 2;   // 33,554,432
    const size_t SZ_WBF = (size_t)C_DIM * C_DIM * 2;    //  8,388,608
    char* ws = (char*)d_ws;
    size_t off = 0;
    __hip_bfloat16* S0 = (__hip_bfloat16*)(ws + off); off += SZ_XBF; // xr -> v
    __hip_bfloat16* S1 = (__hip_bfloat16*)(ws + off); off += SZ_XBF; // xk -> r
    __hip_bfloat16* S2 = (__hip_bfloat16*)(ws + off); off += SZ_XBF; // xv -> v2/y
    __hip_bfloat16* S3 = (__hip_bfloat16*)(ws + off); off += SZ_XBF; // xw -> k~
    __hip_bfloat16* S4 = (__hip_bfloat16*)(ws + off); off += SZ_XBF; // xv2
    char* D = ws + off; off += (size_t)M_ROWS * C_DIM * 4;  // XX||H, then decay
    __hip_bfloat16* XX    = (__hip_bfloat16*)D;
    float*          Hbuf  = (float*)(D + SZ_XBF);           // [8192][256] fp32
    float*          decay = (float*)D;
    __hip_bfloat16* WrT = (__hip_bfloat16*)(ws + off); off += SZ_WBF;
    __hip_bfloat16* WkT = (__hip_bfloat16*)(ws + off); off += SZ_WBF;
    __hip_bfloat16* WvT = (__hip_bfloat16*)(ws + off); off += SZ_WBF;
    __hip_bfloat16* WoT = (__hip_bfloat16*)(ws + off); off += SZ_WBF;
    __hip_bfloat16* w1tb  = (__hip_bfloat16*)(ws + off); off += (size_t)256 * 2048 * 2;
    __hip_bfloat16* dw1t  = (__hip_bfloat16*)(ws + off); off += (size_t)64 * 2048 * 2;
    __hip_bfloat16* vw1t  = (__hip_bfloat16*)(ws + off); off += (size_t)64 * 2048 * 2;
    __hip_bfloat16* dw2t  = (__hip_bfloat16*)(ws + off); off += (size_t)2048 * 64 * 2;
    __hip_bfloat16* vw2t  = (__hip_bfloat16*)(ws + off); off += (size_t)2048 * 64 * 2;
    __hip_bfloat16* Gd    = (__hip_bfloat16*)(ws + off); off += (size_t)M_ROWS * 64 * 2;
    __hip_bfloat16* Gv    = (__hip_bfloat16*)(ws + off); off += (size_t)M_ROWS * 64 * 2;
    if (ws_size < off) {
        fprintf(stderr, "kernel_launch: ws too small (%zu < %zu)\n", ws_size, off);
        return;
    }

    float* out_y     = (float*)d_out;
    float* out_xlast = out_y + (size_t)M_ROWS * C_DIM;
    float* out_state = out_xlast + (size_t)B_DIM * C_DIM;

    // ---- weight prep ----
    k_transpose<<<dim3(8, 64),  256, 0, stream>>>(w1,  w1tb, 2048, 160, 1);
    k_transpose<<<dim3(2, 64),  256, 0, stream>>>(dw1, dw1t, 2048, 64, 1);
    k_transpose<<<dim3(2, 64),  256, 0, stream>>>(vw1, vw1t, 2048, 64, 1);
    k_transpose<<<dim3(64, 2),  256, 0, stream>>>(dw2, dw2t, 64, 2048, 1);
    k_transpose<<<dim3(64, 2),  256, 0, stream>>>(vw2, vw2t, 64, 2048, 1);
    k_transpose<<<dim3(64, 64), 256, 0, stream>>>(Wr, WrT, 2048, 2048, 1);
    k_transpose<<<dim3(64, 64), 256, 0, stream>>>(Wk, WkT, 2048, 2048, 1);
    k_transpose<<<dim3(64, 64), 256, 0, stream>>>(Wv, WvT, 2048, 2048, 1);
    k_transpose<<<dim3(64, 64), 256, 0, stream>>>(Wo, WoT, 2048, 2048, 1);

    // ---- mixer: XX -> H -> mix-apply ----
    k_xx<<<M_ROWS, 256, 0, stream>>>(x, shift, tmx, XX, out_xlast);
    k_gemm_h<<<128, 256, 0, stream>>>(XX, w1tb, Hbuf);
    k_mixapply<<<512, 256, 0, stream>>>(x, shift, Hbuf, w2,
                                        tmr, tmk, tmv, tmw, tmv2,
                                        S0, S1, S2, S3, S4);
    // ---- decay LoRA: Gd = tanh(xw@dw1); decay = exp(-exp(Gd@dw2 + tdec)) ----
    k_gemm_n64<<<128, 256, 0, stream>>>(S3, dw1t, Gd);          // frees S3 next
    k_gemm<<<dim3(16, 64), 256, 0, stream>>>(Gd, dw2t, 64, 3, decay, nullptr, tdec);
    // ---- big GEMMs (outputs recycle freed x-slots) ----
    k_gemm<<<dim3(16, 64), 256, 0, stream>>>(S1, WkT, 2048, 2, nullptr, S3, decay); // k~
    k_gemm<<<dim3(16, 64), 256, 0, stream>>>(S0, WrT, 2048, 1, nullptr, S1, nullptr); // r
    k_gemm<<<dim3(16, 64), 256, 0, stream>>>(S2, WvT, 2048, 1, nullptr, S0, nullptr); // v
    k_gemm<<<dim3(16, 64), 256, 0, stream>>>(S4, WvT, 2048, 1, nullptr, S2, nullptr); // v2
    // ---- v2 LoRA: Gv = tanh(xv2@vw1); v2 += Gv@vw2 ----
    k_gemm_n64<<<128, 256, 0, stream>>>(S4, vw1t, Gv);
    k_gemm<<<dim3(16, 64), 256, 0, stream>>>(Gv, vw2t, 64, 4, nullptr, S2, nullptr);
    // ---- WKV scan (adds v2 in-place into S2) ----
    k_scan<<<128, 64, 0, stream>>>(S1, S3, S0, decay, wkvin, S2, out_state);
    // ---- LayerNorm (in-place) + output projection ----
    k_addln<<<M_ROWS, 256, 0, stream>>>(S2, lnw, lnb);
    k_gemm<<<dim3(16, 64), 256, 0, stream>>>(S2, WoT, 2048, 0, out_y, nullptr, nullptr);

    (void)in_sizes; (void)n_in; (void)out_size;
}

// Round 3
// 1397.312 us; speedup vs baseline: 4.4257x; 4.4257x over previous
//
#include <hip/hip_runtime.h>
#include <hip/hip_bf16.h>
#include <cstdio>

// ---------------------------------------------------------------------------
// RWKV6 TimeMix: B=4, T=2048, C=2048, H=32, N=64, DMIX=32, DDEC=64
// ---------------------------------------------------------------------------

typedef __attribute__((ext_vector_type(8))) short bf16x8;    // 8 bf16 = 4 VGPRs
typedef __attribute__((ext_vector_type(4))) float floatx4;

#define T_DIM 2048
#define C_DIM 2048
#define B_DIM 4
#define M_ROWS (B_DIM * T_DIM)   // 8192

// ---------------- global_load_lds helper (16B per lane) --------------------
typedef const unsigned int __attribute__((address_space(1)))* gas1_t;
typedef unsigned int __attribute__((address_space(3)))* las3_t;
__device__ __forceinline__ void gl_lds16(const void* g, void* l) {
    __builtin_amdgcn_global_load_lds((gas1_t)g, (las3_t)l, 16, 0, 0);
}

// ---------------- transpose + cast + zero-pad ------------------------------
__global__ __launch_bounds__(256) void k_transpose(
    const float* __restrict__ in, void* __restrict__ out,
    int R, int Cin, int to_bf16)
{
    __shared__ float tile[32][33];
    const int tx = threadIdx.x & 31, ty = threadIdx.x >> 5;
    const int cbase = blockIdx.x * 32, rbase = blockIdx.y * 32;
#pragma unroll
    for (int i = 0; i < 4; i++) {
        int r = rbase + ty + i * 8;
        int c = cbase + tx;
        tile[ty + i * 8][tx] = (c < Cin) ? in[(size_t)r * Cin + c] : 0.0f;
    }
    __syncthreads();
    if (to_bf16) {
        __hip_bfloat16* ob = (__hip_bfloat16*)out;
#pragma unroll
        for (int i = 0; i < 4; i++) {
            int c = cbase + ty + i * 8;
            ob[(size_t)c * R + rbase + tx] = __float2bfloat16(tile[tx][ty + i * 8]);
        }
    } else {
        float* of = (float*)out;
#pragma unroll
        for (int i = 0; i < 4; i++) {
            int c = cbase + ty + i * 8;
            of[(size_t)c * R + rbase + tx] = tile[tx][ty + i * 8];
        }
    }
}

// ---------------- XX = bf16(x + (prev-x)*tmx); also x_last ------------------
__global__ __launch_bounds__(256) void k_xx(
    const float* __restrict__ x, const float* __restrict__ shift,
    const float* __restrict__ tmx,
    __hip_bfloat16* __restrict__ XX, float* __restrict__ xlast)
{
    const int row = blockIdx.x;
    const int b = row >> 11, t = row & 2047;
    const int c0 = threadIdx.x * 8;
    const float* xrow = x + (size_t)row * C_DIM;
    const float* prow = (t == 0) ? (shift + (size_t)b * C_DIM) : (xrow - C_DIM);
    float4 xa = ((const float4*)(xrow + c0))[0];
    float4 xb = ((const float4*)(xrow + c0))[1];
    float4 pa = ((const float4*)(prow + c0))[0];
    float4 pb = ((const float4*)(prow + c0))[1];
    float xv8[8] = {xa.x, xa.y, xa.z, xa.w, xb.x, xb.y, xb.z, xb.w};
    float pv8[8] = {pa.x, pa.y, pa.z, pa.w, pb.x, pb.y, pb.z, pb.w};
    union { bf16x8 v8; __hip_bfloat16 e[8]; } u;
#pragma unroll
    for (int j = 0; j < 8; j++)
        u.e[j] = __float2bfloat16(fmaf(pv8[j] - xv8[j], tmx[c0 + j], xv8[j]));
    *(bf16x8*)(XX + (size_t)row * C_DIM + c0) = u.v8;
    if (t == T_DIM - 1) {
        ((float4*)(xlast + (size_t)b * C_DIM + c0))[0] = xa;
        ((float4*)(xlast + (size_t)b * C_DIM + c0))[1] = xb;
    }
}

// ---------------- H = tanh(XX @ w1) : M=8192, N=256(padded), K=2048 ---------
__global__ __launch_bounds__(256) void k_gemm_h(
    const __hip_bfloat16* __restrict__ A,
    const __hip_bfloat16* __restrict__ Bt,
    float* __restrict__ Hout)
{
    __shared__ __hip_bfloat16 As[64 * 32];
    __shared__ __hip_bfloat16 Bs[256 * 32];
    const int tid = threadIdx.x;
    const int m0 = blockIdx.x * 64;
    const int wave = tid >> 6, lane = tid & 63;
    const int fcol = lane & 15, quad = lane >> 4;
    floatx4 acc[16];
#pragma unroll
    for (int i = 0; i < 16; i++) acc[i] = (floatx4){0.f, 0.f, 0.f, 0.f};

    const int rA = tid >> 2, kcA = (tid & 3) * 8;
    const __hip_bfloat16* gA = A + (size_t)(m0 + rA) * 2048 + kcA;
    __hip_bfloat16* lA = As + tid * 8;
    const __hip_bfloat16* gB[4];
    __hip_bfloat16* lB[4];
#pragma unroll
    for (int s = 0; s < 4; s++) {
        int q = tid + 256 * s;
        gB[s] = Bt + (size_t)(q >> 2) * 2048 + (q & 3) * 8;
        lB[s] = Bs + q * 8;
    }
    for (int kk = 0; kk < 2048; kk += 32) {
        gl_lds16(gA + kk, lA);
#pragma unroll
        for (int s = 0; s < 4; s++) gl_lds16(gB[s] + kk, lB[s]);
        __syncthreads();
        bf16x8 aF = *(const bf16x8*)(As + (wave * 16 + fcol) * 32 + quad * 8);
#pragma unroll
        for (int ni = 0; ni < 16; ni++) {
            bf16x8 bF = *(const bf16x8*)(Bs + (ni * 16 + fcol) * 32 + quad * 8);
            acc[ni] = __builtin_amdgcn_mfma_f32_16x16x32_bf16(aF, bF, acc[ni], 0, 0, 0);
        }
        __syncthreads();
    }
#pragma unroll
    for (int ni = 0; ni < 16; ni++) {
        int col = ni * 16 + fcol;
#pragma unroll
        for (int g = 0; g < 4; g++) {
            int row = m0 + wave * 16 + quad * 4 + g;
            Hout[(size_t)row * 256 + col] = tanhf(acc[ni][g]);
        }
    }
}

// ---------------- G = tanh(A @ Bt^T) : N=64, K=2048 -------------------------
__global__ __launch_bounds__(256) void k_gemm_n64(
    const __hip_bfloat16* __restrict__ A,
    const __hip_bfloat16* __restrict__ Bt,
    __hip_bfloat16* __restrict__ G)
{
    __shared__ __hip_bfloat16 As[64 * 32];
    __shared__ __hip_bfloat16 Bs[64 * 32];
    const int tid = threadIdx.x;
    const int m0 = blockIdx.x * 64;
    const int wave = tid >> 6, lane = tid & 63;
    const int fcol = lane & 15, quad = lane >> 4;
    floatx4 acc[4];
#pragma unroll
    for (int i = 0; i < 4; i++) acc[i] = (floatx4){0.f, 0.f, 0.f, 0.f};

    const int r = tid >> 2, kc = (tid & 3) * 8;
    const __hip_bfloat16* gA = A + (size_t)(m0 + r) * 2048 + kc;
    const __hip_bfloat16* gB = Bt + (size_t)r * 2048 + kc;
    __hip_bfloat16* lA = As + tid * 8;
    __hip_bfloat16* lB = Bs + tid * 8;
    for (int kk = 0; kk < 2048; kk += 32) {
        gl_lds16(gA + kk, lA);
        gl_lds16(gB + kk, lB);
        __syncthreads();
        bf16x8 aF = *(const bf16x8*)(As + (wave * 16 + fcol) * 32 + quad * 8);
#pragma unroll
        for (int ni = 0; ni < 4; ni++) {
            bf16x8 bF = *(const bf16x8*)(Bs + (ni * 16 + fcol) * 32 + quad * 8);
            acc[ni] = __builtin_amdgcn_mfma_f32_16x16x32_bf16(aF, bF, acc[ni], 0, 0, 0);
        }
        __syncthreads();
    }
#pragma unroll
    for (int ni = 0; ni < 4; ni++) {
        int col = ni * 16 + fcol;
#pragma unroll
        for (int g = 0; g < 4; g++) {
            int row = m0 + wave * 16 + quad * 4 + g;
            G[(size_t)row * 64 + col] = __float2bfloat16(tanhf(acc[ni][g]));
        }
    }
}

// ---------------- mix-apply: xout_f = x + dx*(maa_f + H_f @ w2_f) -----------
__global__ __launch_bounds__(256) void k_mixapply(
    const float* __restrict__ x, const float* __restrict__ shift,
    const float* __restrict__ H, const float* __restrict__ w2,
    const float* __restrict__ tmr, const float* __restrict__ tmk,
    const float* __restrict__ tmv, const float* __restrict__ tmw,
    const float* __restrict__ tmv2,
    __hip_bfloat16* __restrict__ xr, __hip_bfloat16* __restrict__ xk,
    __hip_bfloat16* __restrict__ xv, __hip_bfloat16* __restrict__ xw,
    __hip_bfloat16* __restrict__ xv2)
{
    __shared__ float hsm[16][160];
    const int row0 = blockIdx.x * 16;
    const int b = row0 >> 11;
    const int tid = threadIdx.x;
    for (int idx = tid; idx < 16 * 160; idx += 256)
        hsm[idx / 160][idx % 160] = H[(size_t)(row0 + idx / 160) * 256 + idx % 160];
    __syncthreads();
    const int c0 = tid * 8;
    const float* maas[5] = {tmr, tmk, tmv, tmw, tmv2};
    __hip_bfloat16* outs[5] = {xr, xk, xv, xw, xv2};
    for (int rc = 0; rc < 16; rc += 8) {
#pragma unroll
        for (int f = 0; f < 5; f++) {
            float acc[8][8];
#pragma unroll
            for (int r = 0; r < 8; r++)
#pragma unroll
                for (int j = 0; j < 8; j++) acc[r][j] = 0.f;
#pragma unroll 4
            for (int d = 0; d < 32; d++) {
                const float4* wp = (const float4*)(w2 + (size_t)(f * 32 + d) * 2048 + c0);
                float4 p0 = wp[0], p1 = wp[1];
                float wv[8] = {p0.x, p0.y, p0.z, p0.w, p1.x, p1.y, p1.z, p1.w};
#pragma unroll
                for (int r = 0; r < 8; r++) {
                    float h = hsm[rc + r][f * 32 + d];
#pragma unroll
                    for (int j = 0; j < 8; j++) acc[r][j] = fmaf(h, wv[j], acc[r][j]);
                }
            }
            const float* maa = maas[f];
            float m8[8];
#pragma unroll
            for (int j = 0; j < 8; j++) m8[j] = maa[c0 + j];
#pragma unroll
            for (int r = 0; r < 8; r++) {
                int row = row0 + rc + r;
                int t = row & 2047;
                const float* xrow = x + (size_t)row * C_DIM;
                const float* prow = (t == 0) ? (shift + (size_t)b * C_DIM) : (xrow - C_DIM);
                float4 xa = ((const float4*)(xrow + c0))[0];
                float4 xb = ((const float4*)(xrow + c0))[1];
                float4 pa = ((const float4*)(prow + c0))[0];
                float4 pb = ((const float4*)(prow + c0))[1];
                float xv8[8] = {xa.x, xa.y, xa.z, xa.w, xb.x, xb.y, xb.z, xb.w};
                float pv8[8] = {pa.x, pa.y, pa.z, pa.w, pb.x, pb.y, pb.z, pb.w};
                union { bf16x8 v8; __hip_bfloat16 e[8]; } u;
#pragma unroll
                for (int j = 0; j < 8; j++) {
                    float dx = pv8[j] - xv8[j];
                    u.e[j] = __float2bfloat16(fmaf(dx, m8[j] + acc[r][j], xv8[j]));
                }
                *(bf16x8*)(outs[f] + (size_t)row * C_DIM + c0) = u.v8;
            }
        }
    }
}

// ---------------- generic MFMA GEMM: M=8192, N=2048, K param ---------------
// mode 0: outF = val            mode 1: outB = bf16(val)
// mode 2: outB = bf16(val*(1-aux[idx]))   mode 3: outF = exp(-exp(val+aux[col]))
// mode 4: outB += val (bf16 rmw)
__global__ __launch_bounds__(256) void k_gemm(
    const __hip_bfloat16* __restrict__ A,
    const __hip_bfloat16* __restrict__ Bt,
    int K, int mode,
    float* __restrict__ outF, __hip_bfloat16* __restrict__ outB,
    const float* __restrict__ aux)
{
    __shared__ __hip_bfloat16 As[128 * 32];
    __shared__ __hip_bfloat16 Bs[128 * 32];
    const int tid = threadIdx.x;
    const int m0 = blockIdx.y * 128, n0 = blockIdx.x * 128;
    const int wave = tid >> 6, lane = tid & 63;
    const int wm = (wave >> 1) * 64, wn = (wave & 1) * 64;
    const int fcol = lane & 15, quad = lane >> 4;

    floatx4 acc[4][4];
#pragma unroll
    for (int mi = 0; mi < 4; mi++)
#pragma unroll
        for (int ni = 0; ni < 4; ni++)
            acc[mi][ni] = (floatx4){0.f, 0.f, 0.f, 0.f};

    const int q0 = tid, q1 = tid + 256;
    const int r0 = q0 >> 2, kc0 = (q0 & 3) * 8;
    const int r1 = q1 >> 2, kc1 = (q1 & 3) * 8;
    const __hip_bfloat16* gA0 = A + (size_t)(m0 + r0) * K + kc0;
    const __hip_bfloat16* gA1 = A + (size_t)(m0 + r1) * K + kc1;
    const __hip_bfloat16* gB0 = Bt + (size_t)(n0 + r0) * K + kc0;
    const __hip_bfloat16* gB1 = Bt + (size_t)(n0 + r1) * K + kc1;
    __hip_bfloat16* lA0 = As + q0 * 8; __hip_bfloat16* lA1 = As + q1 * 8;
    __hip_bfloat16* lB0 = Bs + q0 * 8; __hip_bfloat16* lB1 = Bs + q1 * 8;

    for (int kk = 0; kk < K; kk += 32) {
        gl_lds16(gA0 + kk, lA0);
        gl_lds16(gA1 + kk, lA1);
        gl_lds16(gB0 + kk, lB0);
        gl_lds16(gB1 + kk, lB1);
        __syncthreads();
        bf16x8 aF[4], bF[4];
#pragma unroll
        for (int mi = 0; mi < 4; mi++)
            aF[mi] = *(const bf16x8*)(As + (wm + mi * 16 + fcol) * 32 + quad * 8);
#pragma unroll
        for (int ni = 0; ni < 4; ni++)
            bF[ni] = *(const bf16x8*)(Bs + (wn + ni * 16 + fcol) * 32 + quad * 8);
#pragma unroll
        for (int mi = 0; mi < 4; mi++)
#pragma unroll
            for (int ni = 0; ni < 4; ni++)
                acc[mi][ni] = __builtin_amdgcn_mfma_f32_16x16x32_bf16(
                    aF[mi], bF[ni], acc[mi][ni], 0, 0, 0);
        __syncthreads();
    }
#pragma unroll
    for (int mi = 0; mi < 4; mi++) {
#pragma unroll
        for (int ni = 0; ni < 4; ni++) {
            int rbase = m0 + wm + mi * 16 + quad * 4;
            int ccol = n0 + wn + ni * 16 + fcol;
#pragma unroll
            for (int g = 0; g < 4; g++) {
                size_t idx = (size_t)(rbase + g) * 2048 + ccol;
                float val = acc[mi][ni][g];
                if (mode == 0) {
                    outF[idx] = val;
                } else if (mode == 1) {
                    outB[idx] = __float2bfloat16(val);
                } else if (mode == 2) {
                    outB[idx] = __float2bfloat16(val * (1.0f - aux[idx]));
                } else if (mode == 3) {
                    outF[idx] = expf(-expf(val + aux[ccol]));
                } else {
                    outB[idx] = __float2bfloat16(__bfloat162float(outB[idx]) + val);
                }
            }
        }
    }
}

// ---------------- chunked WKV scan (flash-linear-attention form) ------------
// One block per (b,h); 4 waves; 32 chunks of L=64, sequential.
// y[t] = (r[t]*Eexc[t]) . S_in + sum_{s<t} ((r*Eexc[t]).(k~/Einc[s])) v[s]
// S_out = diag(Efin) S_in + C^T V,  C[s] = k~[s]*Efin/Einc[s]
// State S held in MFMA C/D frags (wave w owns k-rows [16w,16w+16)).
__global__ __launch_bounds__(256) void k_scan_chunked(
    const __hip_bfloat16* __restrict__ r, const __hip_bfloat16* __restrict__ k,
    const __hip_bfloat16* __restrict__ v, const float* __restrict__ dec,
    const float* __restrict__ state_in,
    __hip_bfloat16* __restrict__ y, float* __restrict__ state_out)
{
    // gl_lds16 targets: must be load-order contiguous (stride 64)
    __shared__ __hip_bfloat16 Rs[64 * 64];
    __shared__ __hip_bfloat16 Ks[64 * 64];
    __shared__ __hip_bfloat16 Vs[64 * 64];
    __shared__ float Ds[64 * 64];
    // MFMA operand tiles: stride 72 (144B) -> 16B-aligned rows, ~2-way banks
    __shared__ __hip_bfloat16 Am[64 * 72];   // a[t][i] = r*Eexc
    __shared__ __hip_bfloat16 Bm[64 * 72];   // b[s][i] = k~/Einc
    __shared__ __hip_bfloat16 VT[64 * 72];   // V^T [j][s]
    __shared__ __hip_bfloat16 CT[64 * 72];   // C^T [i][s]
    __shared__ __hip_bfloat16 ST[64 * 72];   // S^T [j][i] (chunk-start copy)
    __shared__ __hip_bfloat16 Pm[64 * 72];   // masked P [t][s]
    __shared__ float part[4][64];
    __shared__ float efin[64];

    const int tid = threadIdx.x;
    const int bh = blockIdx.x, b = bh >> 5, h = bh & 31;
    const int wave = tid >> 6, lane = tid & 63;
    const int fcol = lane & 15, quad = lane >> 4;
    const int ci = tid & 63, seg = tid >> 6;    // scan-build ids

    // ---- init state frags: S[i][j], wave rows i in [16w,16w+16) ----
    floatx4 sfr[4];
    {
        const float* sp = state_in + (size_t)bh * 4096;
#pragma unroll
        for (int n = 0; n < 4; n++)
#pragma unroll
            for (int g = 0; g < 4; g++)
                sfr[n][g] = sp[(size_t)(16 * wave + quad * 4 + g) * 64 + 16 * n + fcol];
    }

    const size_t cbase0 = (size_t)b * T_DIM * C_DIM + (size_t)h * 64;
    for (int c = 0; c < 32; c++) {
        const size_t cb = cbase0 + (size_t)c * 64 * C_DIM;
        // (a) stage chunk: r,k,v bf16 rows [t][i]; dec fp32
        {
            const int q0 = tid, q1 = tid + 256;
            gl_lds16(r + cb + (size_t)(q0 >> 3) * C_DIM + (q0 & 7) * 8, Rs + q0 * 8);
            gl_lds16(r + cb + (size_t)(q1 >> 3) * C_DIM + (q1 & 7) * 8, Rs + q1 * 8);
            gl_lds16(k + cb + (size_t)(q0 >> 3) * C_DIM + (q0 & 7) * 8, Ks + q0 * 8);
            gl_lds16(k + cb + (size_t)(q1 >> 3) * C_DIM + (q1 & 7) * 8, Ks + q1 * 8);
            gl_lds16(v + cb + (size_t)(q0 >> 3) * C_DIM + (q0 & 7) * 8, Vs + q0 * 8);
            gl_lds16(v + cb + (size_t)(q1 >> 3) * C_DIM + (q1 & 7) * 8, Vs + q1 * 8);
#pragma unroll
            for (int s = 0; s < 4; s++) {
                int q = tid + 256 * s;
                gl_lds16(dec + cb + (size_t)(q >> 4) * C_DIM + (q & 15) * 4, Ds + q * 4);
            }
        }
        __syncthreads();   // B1: loads drained; prev-chunk MFMA LDS reads done

        // (c) S^T copy (bf16) + segment decay products
        {
#pragma unroll
            for (int n = 0; n < 4; n++)
#pragma unroll
                for (int g = 0; g < 4; g++)
                    ST[(size_t)(16 * n + fcol) * 72 + 16 * wave + quad * 4 + g] =
                        __float2bfloat16(sfr[n][g]);
            float p = 1.0f;
#pragma unroll
            for (int u = 0; u < 16; u++) p *= Ds[(seg * 16 + u) * 64 + ci];
            part[seg][ci] = p;
        }
        __syncthreads();   // B2

        // (e) build A, B, C^T; transpose V
        {
            float p0 = part[0][ci], p1 = part[1][ci], p2 = part[2][ci], p3 = part[3][ci];
            float pre = 1.0f;
            if (seg > 0) pre *= p0;
            if (seg > 1) pre *= p1;
            if (seg > 2) pre *= p2;
            float tot = p0 * p1 * p2 * p3;
            if (seg == 0) efin[ci] = tot;
            float e = pre;
#pragma unroll
            for (int u = 0; u < 16; u++) {
                int t = seg * 16 + u;
                float d = Ds[t * 64 + ci];
                float rv = __bfloat162float(Rs[t * 64 + ci]);
                float kv = __bfloat162float(Ks[t * 64 + ci]);
                Am[t * 72 + ci] = __float2bfloat16(rv * e);
                e *= d;
                float bb = kv * __builtin_amdgcn_rcpf(e);
                Bm[t * 72 + ci] = __float2bfloat16(bb);
                CT[ci * 72 + t] = __float2bfloat16(bb * tot);
            }
            // V^T (staggered to spread banks)
#pragma unroll
            for (int u = 0; u < 16; u++) {
                int t = seg * 16 + ((u + (ci & 15)) & 15);
                VT[ci * 72 + t] = Vs[t * 64 + ci];
            }
        }
        __syncthreads();   // B3

        // (g) MFMA phase
        {
            bf16x8 af[2], yb[2];
#pragma unroll
            for (int kk = 0; kk < 2; kk++)
                af[kk] = *(const bf16x8*)(Am + (16 * wave + fcol) * 72 + kk * 32 + quad * 8);
            floatx4 pfr[4], yfr[4];
#pragma unroll
            for (int n = 0; n < 4; n++) {
                pfr[n] = (floatx4){0.f, 0.f, 0.f, 0.f};
                yfr[n] = (floatx4){0.f, 0.f, 0.f, 0.f};
#pragma unroll
                for (int kk = 0; kk < 2; kk++) {
                    bf16x8 bF = *(const bf16x8*)(Bm + (16 * n + fcol) * 72 + kk * 32 + quad * 8);
                    bf16x8 sF = *(const bf16x8*)(ST + (16 * n + fcol) * 72 + kk * 32 + quad * 8);
                    pfr[n] = __builtin_amdgcn_mfma_f32_16x16x32_bf16(af[kk], bF, pfr[n], 0, 0, 0);
                    yfr[n] = __builtin_amdgcn_mfma_f32_16x16x32_bf16(af[kk], sF, yfr[n], 0, 0, 0);
                }
            }
            // write masked P (own t-rows only -> no cross-wave dependency)
#pragma unroll
            for (int n = 0; n < 4; n++)
#pragma unroll
                for (int g = 0; g < 4; g++) {
                    int t = 16 * wave + quad * 4 + g;
                    int s = 16 * n + fcol;
                    Pm[t * 72 + s] = (s < t) ? __float2bfloat16(pfr[n][g])
                                             : __float2bfloat16(0.0f);
                }
            // scale state by chunk decay
            float eg[4];
#pragma unroll
            for (int g = 0; g < 4; g++) eg[g] = efin[16 * wave + quad * 4 + g];
#pragma unroll
            for (int n = 0; n < 4; n++)
#pragma unroll
                for (int g = 0; g < 4; g++) sfr[n][g] *= eg[g];
            // Yintra += Pm @ V ; S += C^T @ V
            bf16x8 pf[2], cf[2];
#pragma unroll
            for (int kk = 0; kk < 2; kk++) {
                pf[kk] = *(const bf16x8*)(Pm + (16 * wave + fcol) * 72 + kk * 32 + quad * 8);
                cf[kk] = *(const bf16x8*)(CT + (16 * wave + fcol) * 72 + kk * 32 + quad * 8);
            }
#pragma unroll
            for (int n = 0; n < 4; n++) {
#pragma unroll
                for (int kk = 0; kk < 2; kk++) {
                    bf16x8 vF = *(const bf16x8*)(VT + (16 * n + fcol) * 72 + kk * 32 + quad * 8);
                    yfr[n] = __builtin_amdgcn_mfma_f32_16x16x32_bf16(pf[kk], vF, yfr[n], 0, 0, 0);
                    sfr[n] = __builtin_amdgcn_mfma_f32_16x16x32_bf16(cf[kk], vF, sfr[n], 0, 0, 0);
                }
            }
            // write y (+= v2 already resident in y buffer)
#pragma unroll
            for (int n = 0; n < 4; n++)
#pragma unroll
                for (int g = 0; g < 4; g++) {
                    size_t addr = cb + (size_t)(16 * wave + quad * 4 + g) * C_DIM + 16 * n + fcol;
                    float yv = __bfloat162float(y[addr]) + yfr[n][g];
                    y[addr] = __float2bfloat16(yv);
                }
        }
    }
    // ---- write final state ----
    {
        float* so = state_out + (size_t)bh * 4096;
#pragma unroll
        for (int n = 0; n < 4; n++)
#pragma unroll
            for (int g = 0; g < 4; g++)
                so[(size_t)(16 * wave + quad * 4 + g) * 64 + 16 * n + fcol] = sfr[n][g];
    }
}

// ---------------- in-place LayerNorm on bf16 rows ---------------------------
__global__ __launch_bounds__(256) void k_addln(
    __hip_bfloat16* __restrict__ y,
    const float* __restrict__ lnw, const float* __restrict__ lnb)
{
    __shared__ float ls[4], ls2[4];
    const int row = blockIdx.x;
    const size_t base = (size_t)row * C_DIM;
    const int tid = threadIdx.x;
    const int c0 = tid * 8;
    union { bf16x8 v8; __hip_bfloat16 e[8]; } uin;
    uin.v8 = *(const bf16x8*)(y + base + c0);
    float vbuf[8];
#pragma unroll
    for (int j = 0; j < 8; j++) vbuf[j] = __bfloat162float(uin.e[j]);
    float s = 0.f, s2 = 0.f;
#pragma unroll
    for (int j = 0; j < 8; j++) { s += vbuf[j]; s2 += vbuf[j] * vbuf[j]; }
#pragma unroll
    for (int off = 32; off > 0; off >>= 1) {
        s += __shfl_down(s, off, 64);
        s2 += __shfl_down(s2, off, 64);
    }
    const int w = tid >> 6;
    if ((tid & 63) == 0) { ls[w] = s; ls2[w] = s2; }
    __syncthreads();
    float S = ls[0] + ls[1] + ls[2] + ls[3];
    float S2 = ls2[0] + ls2[1] + ls2[2] + ls2[3];
    float mu = S * (1.0f / C_DIM);
    float var = S2 * (1.0f / C_DIM) - mu * mu;
    float rs = rsqrtf(var + 1e-5f);
    union { bf16x8 v8; __hip_bfloat16 e[8]; } u;
#pragma unroll
    for (int j = 0; j < 8; j++) {
        int ccc = c0 + j;
        u.e[j] = __float2bfloat16((vbuf[j] - mu) * rs * lnw[ccc] + lnb[ccc]);
    }
    *(bf16x8*)(y + base + c0) = u.v8;
}

// ---------------------------------------------------------------------------
extern "C" void kernel_launch(void* const* d_in, const int* in_sizes, int n_in,
                              void* d_out, int out_size, void* d_ws, size_t ws_size,
                              hipStream_t stream)
{
    const float* x     = (const float*)d_in[0];
    const float* shift = (const float*)d_in[1];
    const float* wkvin = (const float*)d_in[2];
    const float* tmx   = (const float*)d_in[3];
    const float* tmr   = (const float*)d_in[4];
    const float* tmk   = (const float*)d_in[5];
    const float* tmv   = (const float*)d_in[6];
    const float* tmw   = (const float*)d_in[7];
    const float* tmv2  = (const float*)d_in[8];
    const float* w1    = (const float*)d_in[9];
    const float* w2    = (const float*)d_in[10];
    const float* tdec  = (const float*)d_in[11];
    const float* dw1   = (const float*)d_in[12];
    const float* dw2   = (const float*)d_in[13];
    const float* vw1   = (const float*)d_in[14];
    const float* vw2   = (const float*)d_in[15];
    const float* Wr    = (const float*)d_in[16];
    const float* Wk    = (const float*)d_in[17];
    const float* Wv    = (const float*)d_in[18];
    const float* Wo    = (const float*)d_in[19];
    const float* lnw   = (const float*)d_in[20];
    const float* lnb   = (const float*)d_in[21];

    const size_t SZ_XBF = (size_t)M_ROWS * C_DIM * 2;
    const size_t SZ_WBF = (size_t)C_DIM * C_DIM * 2;
    char* ws = (char*)d_ws;
    size_t off = 0;
    __hip_bfloat16* S0 = (__hip_bfloat16*)(ws + off); off += SZ_XBF; // xr -> v
    __hip_bfloat16* S1 = (__hip_bfloat16*)(ws + off); off += SZ_XBF; // xk -> r
    __hip_bfloat16* S2 = (__hip_bfloat16*)(ws + off); off += SZ_XBF; // xv -> v2/y
    __hip_bfloat16* S3 = (__hip_bfloat16*)(ws + off); off += SZ_XBF; // xw -> k~
    __hip_bfloat16* S4 = (__hip_bfloat16*)(ws + off); off += SZ_XBF; // xv2
    char* D = ws + off; off += (size_t)M_ROWS * C_DIM * 4;  // XX||H, then decay
    __hip_bfloat16* XX    = (__hip_bfloat16*)D;
    float*          Hbuf  = (float*)(D + SZ_XBF);
    float*          decay = (float*)D;
    __hip_bfloat16* WrT = (__hip_bfloat16*)(ws + off); off += SZ_WBF;
    __hip_bfloat16* WkT = (__hip_bfloat16*)(ws + off); off += SZ_WBF;
    __hip_bfloat16* WvT = (__hip_bfloat16*)(ws + off); off += SZ_WBF;
    __hip_bfloat16* WoT = (__hip_bfloat16*)(ws + off); off += SZ_WBF;
    __hip_bfloat16* w1tb  = (__hip_bfloat16*)(ws + off); off += (size_t)256 * 2048 * 2;
    __hip_bfloat16* dw1t  = (__hip_bfloat16*)(ws + off); off += (size_t)64 * 2048 * 2;
    __hip_bfloat16* vw1t  = (__hip_bfloat16*)(ws + off); off += (size_t)64 * 2048 * 2;
    __hip_bfloat16* dw2t  = (__hip_bfloat16*)(ws + off); off += (size_t)2048 * 64 * 2;
    __hip_bfloat16* vw2t  = (__hip_bfloat16*)(ws + off); off += (size_t)2048 * 64 * 2;
    __hip_bfloat16* Gd    = (__hip_bfloat16*)(ws + off); off += (size_t)M_ROWS * 64 * 2;
    __hip_bfloat16* Gv    = (__hip_bfloat16*)(ws + off); off += (size_t)M_ROWS * 64 * 2;
    if (ws_size < off) {
        fprintf(stderr, "kernel_launch: ws too small (%zu < %zu)\n", ws_size, off);
        return;
    }

    float* out_y     = (float*)d_out;
    float* out_xlast = out_y + (size_t)M_ROWS * C_DIM;
    float* out_state = out_xlast + (size_t)B_DIM * C_DIM;

    // ---- weight prep ----
    k_transpose<<<dim3(8, 64),  256, 0, stream>>>(w1,  w1tb, 2048, 160, 1);
    k_transpose<<<dim3(2, 64),  256, 0, stream>>>(dw1, dw1t, 2048, 64, 1);
    k_transpose<<<dim3(2, 64),  256, 0, stream>>>(vw1, vw1t, 2048, 64, 1);
    k_transpose<<<dim3(64, 2),  256, 0, stream>>>(dw2, dw2t, 64, 2048, 1);
    k_transpose<<<dim3(64, 2),  256, 0, stream>>>(vw2, vw2t, 64, 2048, 1);
    k_transpose<<<dim3(64, 64), 256, 0, stream>>>(Wr, WrT, 2048, 2048, 1);
    k_transpose<<<dim3(64, 64), 256, 0, stream>>>(Wk, WkT, 2048, 2048, 1);
    k_transpose<<<dim3(64, 64), 256, 0, stream>>>(Wv, WvT, 2048, 2048, 1);
    k_transpose<<<dim3(64, 64), 256, 0, stream>>>(Wo, WoT, 2048, 2048, 1);

    // ---- mixer ----
    k_xx<<<M_ROWS, 256, 0, stream>>>(x, shift, tmx, XX, out_xlast);
    k_gemm_h<<<128, 256, 0, stream>>>(XX, w1tb, Hbuf);
    k_mixapply<<<512, 256, 0, stream>>>(x, shift, Hbuf, w2,
                                        tmr, tmk, tmv, tmw, tmv2,
                                        S0, S1, S2, S3, S4);
    // ---- decay LoRA ----
    k_gemm_n64<<<128, 256, 0, stream>>>(S3, dw1t, Gd);
    k_gemm<<<dim3(16, 64), 256, 0, stream>>>(Gd, dw2t, 64, 3, decay, nullptr, tdec);
    // ---- big GEMMs ----
    k_gemm<<<dim3(16, 64), 256, 0, stream>>>(S1, WkT, 2048, 2, nullptr, S3, decay); // k~
    k_gemm<<<dim3(16, 64), 256, 0, stream>>>(S0, WrT, 2048, 1, nullptr, S1, nullptr); // r
    k_gemm<<<dim3(16, 64), 256, 0, stream>>>(S2, WvT, 2048, 1, nullptr, S0, nullptr); // v
    k_gemm<<<dim3(16, 64), 256, 0, stream>>>(S4, WvT, 2048, 1, nullptr, S2, nullptr); // v2
    // ---- v2 LoRA ----
    k_gemm_n64<<<128, 256, 0, stream>>>(S4, vw1t, Gv);
    k_gemm<<<dim3(16, 64), 256, 0, stream>>>(Gv, vw2t, 64, 4, nullptr, S2, nullptr);
    // ---- chunked WKV scan (adds v2 in-place into S2) ----
    k_scan_chunked<<<128, 256, 0, stream>>>(S1, S3, S0, decay, wkvin, S2, out_state);
    // ---- LayerNorm (in-place) + output projection ----
    k_addln<<<M_ROWS, 256, 0, stream>>>(S2, lnw, lnb);
    k_gemm<<<dim3(16, 64), 256, 0, stream>>>(S2, WoT, 2048, 0, out_y, nullptr, nullptr);

    (void)in_sizes; (void)n_in; (void)out_size;
}

// Round 4
// 1290.400 us; speedup vs baseline: 4.7924x; 1.0829x over previous
//
#include <hip/hip_runtime.h>
#include <hip/hip_bf16.h>
#include <cstdio>

// ---------------------------------------------------------------------------
// RWKV6 TimeMix: B=4, T=2048, C=2048, H=32, N=64, DMIX=32, DDEC=64
// ---------------------------------------------------------------------------

typedef __attribute__((ext_vector_type(8))) short bf16x8;    // 8 bf16 = 4 VGPRs
typedef __attribute__((ext_vector_type(4))) float floatx4;

#define T_DIM 2048
#define C_DIM 2048
#define B_DIM 4
#define M_ROWS (B_DIM * T_DIM)   // 8192

// ---------------- global_load_lds helper (16B per lane) --------------------
typedef const unsigned int __attribute__((address_space(1)))* gas1_t;
typedef unsigned int __attribute__((address_space(3)))* las3_t;
__device__ __forceinline__ void gl_lds16(const void* g, void* l) {
    __builtin_amdgcn_global_load_lds((gas1_t)g, (las3_t)l, 16, 0, 0);
}

// ---------------- transpose + cast + zero-pad ------------------------------
__global__ __launch_bounds__(256) void k_transpose(
    const float* __restrict__ in, void* __restrict__ out,
    int R, int Cin, int to_bf16)
{
    __shared__ float tile[32][33];
    const int tx = threadIdx.x & 31, ty = threadIdx.x >> 5;
    const int cbase = blockIdx.x * 32, rbase = blockIdx.y * 32;
#pragma unroll
    for (int i = 0; i < 4; i++) {
        int r = rbase + ty + i * 8;
        int c = cbase + tx;
        tile[ty + i * 8][tx] = (c < Cin) ? in[(size_t)r * Cin + c] : 0.0f;
    }
    __syncthreads();
    if (to_bf16) {
        __hip_bfloat16* ob = (__hip_bfloat16*)out;
#pragma unroll
        for (int i = 0; i < 4; i++) {
            int c = cbase + ty + i * 8;
            ob[(size_t)c * R + rbase + tx] = __float2bfloat16(tile[tx][ty + i * 8]);
        }
    } else {
        float* of = (float*)out;
#pragma unroll
        for (int i = 0; i < 4; i++) {
            int c = cbase + ty + i * 8;
            of[(size_t)c * R + rbase + tx] = tile[tx][ty + i * 8];
        }
    }
}

// ---------------- XX = bf16(x + (prev-x)*tmx); also x_last ------------------
__global__ __launch_bounds__(256) void k_xx(
    const float* __restrict__ x, const float* __restrict__ shift,
    const float* __restrict__ tmx,
    __hip_bfloat16* __restrict__ XX, float* __restrict__ xlast)
{
    const int row = blockIdx.x;
    const int b = row >> 11, t = row & 2047;
    const int c0 = threadIdx.x * 8;
    const float* xrow = x + (size_t)row * C_DIM;
    const float* prow = (t == 0) ? (shift + (size_t)b * C_DIM) : (xrow - C_DIM);
    float4 xa = ((const float4*)(xrow + c0))[0];
    float4 xb = ((const float4*)(xrow + c0))[1];
    float4 pa = ((const float4*)(prow + c0))[0];
    float4 pb = ((const float4*)(prow + c0))[1];
    float xv8[8] = {xa.x, xa.y, xa.z, xa.w, xb.x, xb.y, xb.z, xb.w};
    float pv8[8] = {pa.x, pa.y, pa.z, pa.w, pb.x, pb.y, pb.z, pb.w};
    union { bf16x8 v8; __hip_bfloat16 e[8]; } u;
#pragma unroll
    for (int j = 0; j < 8; j++)
        u.e[j] = __float2bfloat16(fmaf(pv8[j] - xv8[j], tmx[c0 + j], xv8[j]));
    *(bf16x8*)(XX + (size_t)row * C_DIM + c0) = u.v8;
    if (t == T_DIM - 1) {
        ((float4*)(xlast + (size_t)b * C_DIM + c0))[0] = xa;
        ((float4*)(xlast + (size_t)b * C_DIM + c0))[1] = xb;
    }
}

// ---------------- H = tanh(XX @ w1) : M=8192, N=256(padded), K=2048 ---------
__global__ __launch_bounds__(256) void k_gemm_h(
    const __hip_bfloat16* __restrict__ A,
    const __hip_bfloat16* __restrict__ Bt,
    float* __restrict__ Hout)
{
    __shared__ __hip_bfloat16 As[64 * 32];
    __shared__ __hip_bfloat16 Bs[256 * 32];
    const int tid = threadIdx.x;
    const int m0 = blockIdx.x * 64;
    const int wave = tid >> 6, lane = tid & 63;
    const int fcol = lane & 15, quad = lane >> 4;
    floatx4 acc[16];
#pragma unroll
    for (int i = 0; i < 16; i++) acc[i] = (floatx4){0.f, 0.f, 0.f, 0.f};

    const int rA = tid >> 2, kcA = (tid & 3) * 8;
    const __hip_bfloat16* gA = A + (size_t)(m0 + rA) * 2048 + kcA;
    __hip_bfloat16* lA = As + tid * 8;
    const __hip_bfloat16* gB[4];
    __hip_bfloat16* lB[4];
#pragma unroll
    for (int s = 0; s < 4; s++) {
        int q = tid + 256 * s;
        gB[s] = Bt + (size_t)(q >> 2) * 2048 + (q & 3) * 8;
        lB[s] = Bs + q * 8;
    }
    for (int kk = 0; kk < 2048; kk += 32) {
        gl_lds16(gA + kk, lA);
#pragma unroll
        for (int s = 0; s < 4; s++) gl_lds16(gB[s] + kk, lB[s]);
        __syncthreads();
        bf16x8 aF = *(const bf16x8*)(As + (wave * 16 + fcol) * 32 + quad * 8);
#pragma unroll
        for (int ni = 0; ni < 16; ni++) {
            bf16x8 bF = *(const bf16x8*)(Bs + (ni * 16 + fcol) * 32 + quad * 8);
            acc[ni] = __builtin_amdgcn_mfma_f32_16x16x32_bf16(aF, bF, acc[ni], 0, 0, 0);
        }
        __syncthreads();
    }
#pragma unroll
    for (int ni = 0; ni < 16; ni++) {
        int col = ni * 16 + fcol;
#pragma unroll
        for (int g = 0; g < 4; g++) {
            int row = m0 + wave * 16 + quad * 4 + g;
            Hout[(size_t)row * 256 + col] = tanhf(acc[ni][g]);
        }
    }
}

// ---------------- G = tanh(A @ Bt^T) : N=64, K=2048 -------------------------
__global__ __launch_bounds__(256) void k_gemm_n64(
    const __hip_bfloat16* __restrict__ A,
    const __hip_bfloat16* __restrict__ Bt,
    __hip_bfloat16* __restrict__ G)
{
    __shared__ __hip_bfloat16 As[64 * 32];
    __shared__ __hip_bfloat16 Bs[64 * 32];
    const int tid = threadIdx.x;
    const int m0 = blockIdx.x * 64;
    const int wave = tid >> 6, lane = tid & 63;
    const int fcol = lane & 15, quad = lane >> 4;
    floatx4 acc[4];
#pragma unroll
    for (int i = 0; i < 4; i++) acc[i] = (floatx4){0.f, 0.f, 0.f, 0.f};

    const int r = tid >> 2, kc = (tid & 3) * 8;
    const __hip_bfloat16* gA = A + (size_t)(m0 + r) * 2048 + kc;
    const __hip_bfloat16* gB = Bt + (size_t)r * 2048 + kc;
    __hip_bfloat16* lA = As + tid * 8;
    __hip_bfloat16* lB = Bs + tid * 8;
    for (int kk = 0; kk < 2048; kk += 32) {
        gl_lds16(gA + kk, lA);
        gl_lds16(gB + kk, lB);
        __syncthreads();
        bf16x8 aF = *(const bf16x8*)(As + (wave * 16 + fcol) * 32 + quad * 8);
#pragma unroll
        for (int ni = 0; ni < 4; ni++) {
            bf16x8 bF = *(const bf16x8*)(Bs + (ni * 16 + fcol) * 32 + quad * 8);
            acc[ni] = __builtin_amdgcn_mfma_f32_16x16x32_bf16(aF, bF, acc[ni], 0, 0, 0);
        }
        __syncthreads();
    }
#pragma unroll
    for (int ni = 0; ni < 4; ni++) {
        int col = ni * 16 + fcol;
#pragma unroll
        for (int g = 0; g < 4; g++) {
            int row = m0 + wave * 16 + quad * 4 + g;
            G[(size_t)row * 64 + col] = __float2bfloat16(tanhf(acc[ni][g]));
        }
    }
}

// ---------------- mix-apply: xout_f = x + dx*(maa_f + H_f @ w2_f) -----------
__global__ __launch_bounds__(256) void k_mixapply(
    const float* __restrict__ x, const float* __restrict__ shift,
    const float* __restrict__ H, const float* __restrict__ w2,
    const float* __restrict__ tmr, const float* __restrict__ tmk,
    const float* __restrict__ tmv, const float* __restrict__ tmw,
    const float* __restrict__ tmv2,
    __hip_bfloat16* __restrict__ xr, __hip_bfloat16* __restrict__ xk,
    __hip_bfloat16* __restrict__ xv, __hip_bfloat16* __restrict__ xw,
    __hip_bfloat16* __restrict__ xv2)
{
    __shared__ float hsm[16][160];
    const int row0 = blockIdx.x * 16;
    const int b = row0 >> 11;
    const int tid = threadIdx.x;
    for (int idx = tid; idx < 16 * 160; idx += 256)
        hsm[idx / 160][idx % 160] = H[(size_t)(row0 + idx / 160) * 256 + idx % 160];
    __syncthreads();
    const int c0 = tid * 8;
    const float* maas[5] = {tmr, tmk, tmv, tmw, tmv2};
    __hip_bfloat16* outs[5] = {xr, xk, xv, xw, xv2};
    for (int rc = 0; rc < 16; rc += 8) {
#pragma unroll
        for (int f = 0; f < 5; f++) {
            float acc[8][8];
#pragma unroll
            for (int r = 0; r < 8; r++)
#pragma unroll
                for (int j = 0; j < 8; j++) acc[r][j] = 0.f;
#pragma unroll 4
            for (int d = 0; d < 32; d++) {
                const float4* wp = (const float4*)(w2 + (size_t)(f * 32 + d) * 2048 + c0);
                float4 p0 = wp[0], p1 = wp[1];
                float wv[8] = {p0.x, p0.y, p0.z, p0.w, p1.x, p1.y, p1.z, p1.w};
#pragma unroll
                for (int r = 0; r < 8; r++) {
                    float h = hsm[rc + r][f * 32 + d];
#pragma unroll
                    for (int j = 0; j < 8; j++) acc[r][j] = fmaf(h, wv[j], acc[r][j]);
                }
            }
            const float* maa = maas[f];
            float m8[8];
#pragma unroll
            for (int j = 0; j < 8; j++) m8[j] = maa[c0 + j];
#pragma unroll
            for (int r = 0; r < 8; r++) {
                int row = row0 + rc + r;
                int t = row & 2047;
                const float* xrow = x + (size_t)row * C_DIM;
                const float* prow = (t == 0) ? (shift + (size_t)b * C_DIM) : (xrow - C_DIM);
                float4 xa = ((const float4*)(xrow + c0))[0];
                float4 xb = ((const float4*)(xrow + c0))[1];
                float4 pa = ((const float4*)(prow + c0))[0];
                float4 pb = ((const float4*)(prow + c0))[1];
                float xv8[8] = {xa.x, xa.y, xa.z, xa.w, xb.x, xb.y, xb.z, xb.w};
                float pv8[8] = {pa.x, pa.y, pa.z, pa.w, pb.x, pb.y, pb.z, pb.w};
                union { bf16x8 v8; __hip_bfloat16 e[8]; } u;
#pragma unroll
                for (int j = 0; j < 8; j++) {
                    float dx = pv8[j] - xv8[j];
                    u.e[j] = __float2bfloat16(fmaf(dx, m8[j] + acc[r][j], xv8[j]));
                }
                *(bf16x8*)(outs[f] + (size_t)row * C_DIM + c0) = u.v8;
            }
        }
    }
}

// ---------------- big MFMA GEMM: M=8192, N=2048, K=2048 ---------------------
// grid 1024 (1D, XCD-swizzled): xcd=id&7 owns m-tiles [8*xcd,8*xcd+8);
// 8 same-n blocks co-resident per XCD -> B-tile + A-slab live in that L2.
// mode 0: outF = val     mode 1: outB = bf16(val)
__global__ __launch_bounds__(256) void k_gemm(
    const __hip_bfloat16* __restrict__ A,
    const __hip_bfloat16* __restrict__ Bt,
    int mode,
    float* __restrict__ outF, __hip_bfloat16* __restrict__ outB)
{
    constexpr int K = 2048;
    __shared__ __hip_bfloat16 As[128 * 32];
    __shared__ __hip_bfloat16 Bs[128 * 32];
    const int tid = threadIdx.x;
    const int id = blockIdx.x;
    const int xcd = id & 7, jj = id >> 3;
    const int m0 = (((xcd << 3) | (jj & 7))) * 128;   // 64 m-tiles
    const int n0 = (jj >> 3) * 128;                   // 16 n-tiles
    const int wave = tid >> 6, lane = tid & 63;
    const int wm = (wave >> 1) * 64, wn = (wave & 1) * 64;
    const int fcol = lane & 15, quad = lane >> 4;

    floatx4 acc[4][4];
#pragma unroll
    for (int mi = 0; mi < 4; mi++)
#pragma unroll
        for (int ni = 0; ni < 4; ni++)
            acc[mi][ni] = (floatx4){0.f, 0.f, 0.f, 0.f};

    const int q0 = tid, q1 = tid + 256;
    const int r0 = q0 >> 2, kc0 = (q0 & 3) * 8;
    const int r1 = q1 >> 2, kc1 = (q1 & 3) * 8;
    const __hip_bfloat16* gA0 = A + (size_t)(m0 + r0) * K + kc0;
    const __hip_bfloat16* gA1 = A + (size_t)(m0 + r1) * K + kc1;
    const __hip_bfloat16* gB0 = Bt + (size_t)(n0 + r0) * K + kc0;
    const __hip_bfloat16* gB1 = Bt + (size_t)(n0 + r1) * K + kc1;
    __hip_bfloat16* lA0 = As + q0 * 8; __hip_bfloat16* lA1 = As + q1 * 8;
    __hip_bfloat16* lB0 = Bs + q0 * 8; __hip_bfloat16* lB1 = Bs + q1 * 8;

    for (int kk = 0; kk < K; kk += 32) {
        gl_lds16(gA0 + kk, lA0);
        gl_lds16(gA1 + kk, lA1);
        gl_lds16(gB0 + kk, lB0);
        gl_lds16(gB1 + kk, lB1);
        __syncthreads();
        bf16x8 aF[4], bF[4];
#pragma unroll
        for (int mi = 0; mi < 4; mi++)
            aF[mi] = *(const bf16x8*)(As + (wm + mi * 16 + fcol) * 32 + quad * 8);
#pragma unroll
        for (int ni = 0; ni < 4; ni++)
            bF[ni] = *(const bf16x8*)(Bs + (wn + ni * 16 + fcol) * 32 + quad * 8);
#pragma unroll
        for (int mi = 0; mi < 4; mi++)
#pragma unroll
            for (int ni = 0; ni < 4; ni++)
                acc[mi][ni] = __builtin_amdgcn_mfma_f32_16x16x32_bf16(
                    aF[mi], bF[ni], acc[mi][ni], 0, 0, 0);
        __syncthreads();
    }
#pragma unroll
    for (int mi = 0; mi < 4; mi++) {
#pragma unroll
        for (int ni = 0; ni < 4; ni++) {
            int rbase = m0 + wm + mi * 16 + quad * 4;
            int ccol = n0 + wn + ni * 16 + fcol;
#pragma unroll
            for (int g = 0; g < 4; g++) {
                size_t idx = (size_t)(rbase + g) * 2048 + ccol;
                float val = acc[mi][ni][g];
                if (mode == 0) outF[idx] = val;
                else           outB[idx] = __float2bfloat16(val);
            }
        }
    }
}

// ---------------- merged K=64 epilogue GEMMs --------------------------------
// grid 2048: op = id>>10. op0: decay = exp(-exp(Gd@dw2t + tdec)) (fp32)
//                         op1: v2  += Gv@vw2t (bf16 rmw)
__global__ __launch_bounds__(256) void k_gemm64(
    const __hip_bfloat16* __restrict__ A0, const __hip_bfloat16* __restrict__ B0,
    const __hip_bfloat16* __restrict__ A1, const __hip_bfloat16* __restrict__ B1,
    float* __restrict__ decayOut, const float* __restrict__ tdec,
    __hip_bfloat16* __restrict__ v2Out)
{
    constexpr int K = 64;
    __shared__ __hip_bfloat16 As[128 * 32];
    __shared__ __hip_bfloat16 Bs[128 * 32];
    const int tid = threadIdx.x;
    const int op = blockIdx.x >> 10;
    const int id = blockIdx.x & 1023;
    const int xcd = id & 7, jj = id >> 3;
    const int m0 = (((xcd << 3) | (jj & 7))) * 128;
    const int n0 = (jj >> 3) * 128;
    const __hip_bfloat16* A = op ? A1 : A0;
    const __hip_bfloat16* Bt = op ? B1 : B0;
    const int wave = tid >> 6, lane = tid & 63;
    const int wm = (wave >> 1) * 64, wn = (wave & 1) * 64;
    const int fcol = lane & 15, quad = lane >> 4;

    floatx4 acc[4][4];
#pragma unroll
    for (int mi = 0; mi < 4; mi++)
#pragma unroll
        for (int ni = 0; ni < 4; ni++)
            acc[mi][ni] = (floatx4){0.f, 0.f, 0.f, 0.f};

    const int q0 = tid, q1 = tid + 256;
    const int r0 = q0 >> 2, kc0 = (q0 & 3) * 8;
    const int r1 = q1 >> 2, kc1 = (q1 & 3) * 8;
    const __hip_bfloat16* gA0 = A + (size_t)(m0 + r0) * K + kc0;
    const __hip_bfloat16* gA1 = A + (size_t)(m0 + r1) * K + kc1;
    const __hip_bfloat16* gB0 = Bt + (size_t)(n0 + r0) * K + kc0;
    const __hip_bfloat16* gB1 = Bt + (size_t)(n0 + r1) * K + kc1;
    __hip_bfloat16* lA0 = As + q0 * 8; __hip_bfloat16* lA1 = As + q1 * 8;
    __hip_bfloat16* lB0 = Bs + q0 * 8; __hip_bfloat16* lB1 = Bs + q1 * 8;

    for (int kk = 0; kk < K; kk += 32) {
        gl_lds16(gA0 + kk, lA0);
        gl_lds16(gA1 + kk, lA1);
        gl_lds16(gB0 + kk, lB0);
        gl_lds16(gB1 + kk, lB1);
        __syncthreads();
        bf16x8 aF[4], bF[4];
#pragma unroll
        for (int mi = 0; mi < 4; mi++)
            aF[mi] = *(const bf16x8*)(As + (wm + mi * 16 + fcol) * 32 + quad * 8);
#pragma unroll
        for (int ni = 0; ni < 4; ni++)
            bF[ni] = *(const bf16x8*)(Bs + (wn + ni * 16 + fcol) * 32 + quad * 8);
#pragma unroll
        for (int mi = 0; mi < 4; mi++)
#pragma unroll
            for (int ni = 0; ni < 4; ni++)
                acc[mi][ni] = __builtin_amdgcn_mfma_f32_16x16x32_bf16(
                    aF[mi], bF[ni], acc[mi][ni], 0, 0, 0);
        __syncthreads();
    }
#pragma unroll
    for (int mi = 0; mi < 4; mi++) {
#pragma unroll
        for (int ni = 0; ni < 4; ni++) {
            int rbase = m0 + wm + mi * 16 + quad * 4;
            int ccol = n0 + wn + ni * 16 + fcol;
#pragma unroll
            for (int g = 0; g < 4; g++) {
                size_t idx = (size_t)(rbase + g) * 2048 + ccol;
                float val = acc[mi][ni][g];
                if (op == 0) {
                    decayOut[idx] = expf(-expf(val + tdec[ccol]));
                } else {
                    v2Out[idx] = __float2bfloat16(__bfloat162float(v2Out[idx]) + val);
                }
            }
        }
    }
}

// ---------------- chunked WKV scan (flash-linear-attention form) ------------
// One block per (b,h); 4 waves; 32 chunks of L=64, sequential.
// k~ = k*(1-d) computed inline from raw k + dec.
__global__ __launch_bounds__(256) void k_scan_chunked(
    const __hip_bfloat16* __restrict__ r, const __hip_bfloat16* __restrict__ k,
    const __hip_bfloat16* __restrict__ v, const float* __restrict__ dec,
    const float* __restrict__ state_in,
    __hip_bfloat16* __restrict__ y, float* __restrict__ state_out)
{
    __shared__ __hip_bfloat16 Rs[64 * 64];
    __shared__ __hip_bfloat16 Ks[64 * 64];
    __shared__ __hip_bfloat16 Vs[64 * 64];
    __shared__ float Ds[64 * 64];
    __shared__ __hip_bfloat16 Am[64 * 72];   // a[t][i] = r*Eexc
    __shared__ __hip_bfloat16 Bm[64 * 72];   // b[s][i] = k~/Einc
    __shared__ __hip_bfloat16 VT[64 * 72];   // V^T [j][s]
    __shared__ __hip_bfloat16 CT[64 * 72];   // C^T [i][s]
    __shared__ __hip_bfloat16 ST[64 * 72];   // S^T [j][i]
    __shared__ __hip_bfloat16 Pm[64 * 72];   // masked P [t][s]
    __shared__ float part[4][64];
    __shared__ float efin[64];

    const int tid = threadIdx.x;
    const int bh = blockIdx.x, b = bh >> 5, h = bh & 31;
    const int wave = tid >> 6, lane = tid & 63;
    const int fcol = lane & 15, quad = lane >> 4;
    const int ci = tid & 63, seg = tid >> 6;

    floatx4 sfr[4];
    {
        const float* sp = state_in + (size_t)bh * 4096;
#pragma unroll
        for (int n = 0; n < 4; n++)
#pragma unroll
            for (int g = 0; g < 4; g++)
                sfr[n][g] = sp[(size_t)(16 * wave + quad * 4 + g) * 64 + 16 * n + fcol];
    }

    const size_t cbase0 = (size_t)b * T_DIM * C_DIM + (size_t)h * 64;
    for (int c = 0; c < 32; c++) {
        const size_t cb = cbase0 + (size_t)c * 64 * C_DIM;
        {
            const int q0 = tid, q1 = tid + 256;
            gl_lds16(r + cb + (size_t)(q0 >> 3) * C_DIM + (q0 & 7) * 8, Rs + q0 * 8);
            gl_lds16(r + cb + (size_t)(q1 >> 3) * C_DIM + (q1 & 7) * 8, Rs + q1 * 8);
            gl_lds16(k + cb + (size_t)(q0 >> 3) * C_DIM + (q0 & 7) * 8, Ks + q0 * 8);
            gl_lds16(k + cb + (size_t)(q1 >> 3) * C_DIM + (q1 & 7) * 8, Ks + q1 * 8);
            gl_lds16(v + cb + (size_t)(q0 >> 3) * C_DIM + (q0 & 7) * 8, Vs + q0 * 8);
            gl_lds16(v + cb + (size_t)(q1 >> 3) * C_DIM + (q1 & 7) * 8, Vs + q1 * 8);
#pragma unroll
            for (int s = 0; s < 4; s++) {
                int q = tid + 256 * s;
                gl_lds16(dec + cb + (size_t)(q >> 4) * C_DIM + (q & 15) * 4, Ds + q * 4);
            }
        }
        __syncthreads();   // B1

        {
#pragma unroll
            for (int n = 0; n < 4; n++)
#pragma unroll
                for (int g = 0; g < 4; g++)
                    ST[(size_t)(16 * n + fcol) * 72 + 16 * wave + quad * 4 + g] =
                        __float2bfloat16(sfr[n][g]);
            float p = 1.0f;
#pragma unroll
            for (int u = 0; u < 16; u++) p *= Ds[(seg * 16 + u) * 64 + ci];
            part[seg][ci] = p;
        }
        __syncthreads();   // B2

        {
            float p0 = part[0][ci], p1 = part[1][ci], p2 = part[2][ci], p3 = part[3][ci];
            float pre = 1.0f;
            if (seg > 0) pre *= p0;
            if (seg > 1) pre *= p1;
            if (seg > 2) pre *= p2;
            float tot = p0 * p1 * p2 * p3;
            if (seg == 0) efin[ci] = tot;
            float e = pre;
#pragma unroll
            for (int u = 0; u < 16; u++) {
                int t = seg * 16 + u;
                float d = Ds[t * 64 + ci];
                float rv = __bfloat162float(Rs[t * 64 + ci]);
                float kv = __bfloat162float(Ks[t * 64 + ci]) * (1.0f - d);  // k~
                Am[t * 72 + ci] = __float2bfloat16(rv * e);
                e *= d;
                float bb = kv * __builtin_amdgcn_rcpf(e);
                Bm[t * 72 + ci] = __float2bfloat16(bb);
                CT[ci * 72 + t] = __float2bfloat16(bb * tot);
            }
#pragma unroll
            for (int u = 0; u < 16; u++) {
                int t = seg * 16 + ((u + (ci & 15)) & 15);
                VT[ci * 72 + t] = Vs[t * 64 + ci];
            }
        }
        __syncthreads();   // B3

        {
            bf16x8 af[2];
#pragma unroll
            for (int kk = 0; kk < 2; kk++)
                af[kk] = *(const bf16x8*)(Am + (16 * wave + fcol) * 72 + kk * 32 + quad * 8);
            floatx4 pfr[4], yfr[4];
#pragma unroll
            for (int n = 0; n < 4; n++) {
                pfr[n] = (floatx4){0.f, 0.f, 0.f, 0.f};
                yfr[n] = (floatx4){0.f, 0.f, 0.f, 0.f};
#pragma unroll
                for (int kk = 0; kk < 2; kk++) {
                    bf16x8 bF = *(const bf16x8*)(Bm + (16 * n + fcol) * 72 + kk * 32 + quad * 8);
                    bf16x8 sF = *(const bf16x8*)(ST + (16 * n + fcol) * 72 + kk * 32 + quad * 8);
                    pfr[n] = __builtin_amdgcn_mfma_f32_16x16x32_bf16(af[kk], bF, pfr[n], 0, 0, 0);
                    yfr[n] = __builtin_amdgcn_mfma_f32_16x16x32_bf16(af[kk], sF, yfr[n], 0, 0, 0);
                }
            }
#pragma unroll
            for (int n = 0; n < 4; n++)
#pragma unroll
                for (int g = 0; g < 4; g++) {
                    int t = 16 * wave + quad * 4 + g;
                    int s = 16 * n + fcol;
                    Pm[t * 72 + s] = (s < t) ? __float2bfloat16(pfr[n][g])
                                             : __float2bfloat16(0.0f);
                }
            float eg[4];
#pragma unroll
            for (int g = 0; g < 4; g++) eg[g] = efin[16 * wave + quad * 4 + g];
#pragma unroll
            for (int n = 0; n < 4; n++)
#pragma unroll
                for (int g = 0; g < 4; g++) sfr[n][g] *= eg[g];
            bf16x8 pf[2], cf[2];
#pragma unroll
            for (int kk = 0; kk < 2; kk++) {
                pf[kk] = *(const bf16x8*)(Pm + (16 * wave + fcol) * 72 + kk * 32 + quad * 8);
                cf[kk] = *(const bf16x8*)(CT + (16 * wave + fcol) * 72 + kk * 32 + quad * 8);
            }
#pragma unroll
            for (int n = 0; n < 4; n++) {
#pragma unroll
                for (int kk = 0; kk < 2; kk++) {
                    bf16x8 vF = *(const bf16x8*)(VT + (16 * n + fcol) * 72 + kk * 32 + quad * 8);
                    yfr[n] = __builtin_amdgcn_mfma_f32_16x16x32_bf16(pf[kk], vF, yfr[n], 0, 0, 0);
                    sfr[n] = __builtin_amdgcn_mfma_f32_16x16x32_bf16(cf[kk], vF, sfr[n], 0, 0, 0);
                }
            }
#pragma unroll
            for (int n = 0; n < 4; n++)
#pragma unroll
                for (int g = 0; g < 4; g++) {
                    size_t addr = cb + (size_t)(16 * wave + quad * 4 + g) * C_DIM + 16 * n + fcol;
                    float yv = __bfloat162float(y[addr]) + yfr[n][g];
                    y[addr] = __float2bfloat16(yv);
                }
        }
    }
    {
        float* so = state_out + (size_t)bh * 4096;
#pragma unroll
        for (int n = 0; n < 4; n++)
#pragma unroll
            for (int g = 0; g < 4; g++)
                so[(size_t)(16 * wave + quad * 4 + g) * 64 + 16 * n + fcol] = sfr[n][g];
    }
}

// ---------------- in-place LayerNorm on bf16 rows ---------------------------
__global__ __launch_bounds__(256) void k_addln(
    __hip_bfloat16* __restrict__ y,
    const float* __restrict__ lnw, const float* __restrict__ lnb)
{
    __shared__ float ls[4], ls2[4];
    const int row = blockIdx.x;
    const size_t base = (size_t)row * C_DIM;
    const int tid = threadIdx.x;
    const int c0 = tid * 8;
    union { bf16x8 v8; __hip_bfloat16 e[8]; } uin;
    uin.v8 = *(const bf16x8*)(y + base + c0);
    float vbuf[8];
#pragma unroll
    for (int j = 0; j < 8; j++) vbuf[j] = __bfloat162float(uin.e[j]);
    float s = 0.f, s2 = 0.f;
#pragma unroll
    for (int j = 0; j < 8; j++) { s += vbuf[j]; s2 += vbuf[j] * vbuf[j]; }
#pragma unroll
    for (int off = 32; off > 0; off >>= 1) {
        s += __shfl_down(s, off, 64);
        s2 += __shfl_down(s2, off, 64);
    }
    const int w = tid >> 6;
    if ((tid & 63) == 0) { ls[w] = s; ls2[w] = s2; }
    __syncthreads();
    float S = ls[0] + ls[1] + ls[2] + ls[3];
    float S2 = ls2[0] + ls2[1] + ls2[2] + ls2[3];
    float mu = S * (1.0f / C_DIM);
    float var = S2 * (1.0f / C_DIM) - mu * mu;
    float rs = rsqrtf(var + 1e-5f);
    union { bf16x8 v8; __hip_bfloat16 e[8]; } u;
#pragma unroll
    for (int j = 0; j < 8; j++) {
        int ccc = c0 + j;
        u.e[j] = __float2bfloat16((vbuf[j] - mu) * rs * lnw[ccc] + lnb[ccc]);
    }
    *(bf16x8*)(y + base + c0) = u.v8;
}

// ---------------------------------------------------------------------------
extern "C" void kernel_launch(void* const* d_in, const int* in_sizes, int n_in,
                              void* d_out, int out_size, void* d_ws, size_t ws_size,
                              hipStream_t stream)
{
    const float* x     = (const float*)d_in[0];
    const float* shift = (const float*)d_in[1];
    const float* wkvin = (const float*)d_in[2];
    const float* tmx   = (const float*)d_in[3];
    const float* tmr   = (const float*)d_in[4];
    const float* tmk   = (const float*)d_in[5];
    const float* tmv   = (const float*)d_in[6];
    const float* tmw   = (const float*)d_in[7];
    const float* tmv2  = (const float*)d_in[8];
    const float* w1    = (const float*)d_in[9];
    const float* w2    = (const float*)d_in[10];
    const float* tdec  = (const float*)d_in[11];
    const float* dw1   = (const float*)d_in[12];
    const float* dw2   = (const float*)d_in[13];
    const float* vw1   = (const float*)d_in[14];
    const float* vw2   = (const float*)d_in[15];
    const float* Wr    = (const float*)d_in[16];
    const float* Wk    = (const float*)d_in[17];
    const float* Wv    = (const float*)d_in[18];
    const float* Wo    = (const float*)d_in[19];
    const float* lnw   = (const float*)d_in[20];
    const float* lnb   = (const float*)d_in[21];

    const size_t SZ_XBF = (size_t)M_ROWS * C_DIM * 2;
    const size_t SZ_WBF = (size_t)C_DIM * C_DIM * 2;
    char* ws = (char*)d_ws;
    size_t off = 0;
    __hip_bfloat16* S0 = (__hip_bfloat16*)(ws + off); off += SZ_XBF; // xr -> v
    __hip_bfloat16* S1 = (__hip_bfloat16*)(ws + off); off += SZ_XBF; // xk -> r
    __hip_bfloat16* S2 = (__hip_bfloat16*)(ws + off); off += SZ_XBF; // xv -> v2/y
    __hip_bfloat16* S3 = (__hip_bfloat16*)(ws + off); off += SZ_XBF; // xw -> k
    __hip_bfloat16* S4 = (__hip_bfloat16*)(ws + off); off += SZ_XBF; // xv2
    char* D = ws + off; off += (size_t)M_ROWS * C_DIM * 4;  // XX||H, then decay
    __hip_bfloat16* XX    = (__hip_bfloat16*)D;
    float*          Hbuf  = (float*)(D + SZ_XBF);
    float*          decay = (float*)D;
    __hip_bfloat16* WrT = (__hip_bfloat16*)(ws + off); off += SZ_WBF;
    __hip_bfloat16* WkT = (__hip_bfloat16*)(ws + off); off += SZ_WBF;
    __hip_bfloat16* WvT = (__hip_bfloat16*)(ws + off); off += SZ_WBF;
    __hip_bfloat16* WoT = (__hip_bfloat16*)(ws + off); off += SZ_WBF;
    __hip_bfloat16* w1tb  = (__hip_bfloat16*)(ws + off); off += (size_t)256 * 2048 * 2;
    __hip_bfloat16* dw1t  = (__hip_bfloat16*)(ws + off); off += (size_t)64 * 2048 * 2;
    __hip_bfloat16* vw1t  = (__hip_bfloat16*)(ws + off); off += (size_t)64 * 2048 * 2;
    __hip_bfloat16* dw2t  = (__hip_bfloat16*)(ws + off); off += (size_t)2048 * 64 * 2;
    __hip_bfloat16* vw2t  = (__hip_bfloat16*)(ws + off); off += (size_t)2048 * 64 * 2;
    __hip_bfloat16* Gd    = (__hip_bfloat16*)(ws + off); off += (size_t)M_ROWS * 64 * 2;
    __hip_bfloat16* Gv    = (__hip_bfloat16*)(ws + off); off += (size_t)M_ROWS * 64 * 2;
    if (ws_size < off) {
        fprintf(stderr, "kernel_launch: ws too small (%zu < %zu)\n", ws_size, off);
        return;
    }

    float* out_y     = (float*)d_out;
    float* out_xlast = out_y + (size_t)M_ROWS * C_DIM;
    float* out_state = out_xlast + (size_t)B_DIM * C_DIM;

    // ---- weight prep ----
    k_transpose<<<dim3(8, 64),  256, 0, stream>>>(w1,  w1tb, 2048, 160, 1);
    k_transpose<<<dim3(2, 64),  256, 0, stream>>>(dw1, dw1t, 2048, 64, 1);
    k_transpose<<<dim3(2, 64),  256, 0, stream>>>(vw1, vw1t, 2048, 64, 1);
    k_transpose<<<dim3(64, 2),  256, 0, stream>>>(dw2, dw2t, 64, 2048, 1);
    k_transpose<<<dim3(64, 2),  256, 0, stream>>>(vw2, vw2t, 64, 2048, 1);
    k_transpose<<<dim3(64, 64), 256, 0, stream>>>(Wr, WrT, 2048, 2048, 1);
    k_transpose<<<dim3(64, 64), 256, 0, stream>>>(Wk, WkT, 2048, 2048, 1);
    k_transpose<<<dim3(64, 64), 256, 0, stream>>>(Wv, WvT, 2048, 2048, 1);
    k_transpose<<<dim3(64, 64), 256, 0, stream>>>(Wo, WoT, 2048, 2048, 1);

    // ---- mixer ----
    k_xx<<<M_ROWS, 256, 0, stream>>>(x, shift, tmx, XX, out_xlast);
    k_gemm_h<<<128, 256, 0, stream>>>(XX, w1tb, Hbuf);
    k_mixapply<<<512, 256, 0, stream>>>(x, shift, Hbuf, w2,
                                        tmr, tmk, tmv, tmw, tmv2,
                                        S0, S1, S2, S3, S4);
    // ---- LoRA hidden layers ----
    k_gemm_n64<<<128, 256, 0, stream>>>(S3, dw1t, Gd);   // from xw (frees S3)
    k_gemm_n64<<<128, 256, 0, stream>>>(S4, vw1t, Gv);   // from xv2
    // ---- big GEMMs (outputs recycle freed x-slots; raw k now) ----
    k_gemm<<<1024, 256, 0, stream>>>(S1, WkT, 1, nullptr, S3);   // k  (xk->S3)
    k_gemm<<<1024, 256, 0, stream>>>(S0, WrT, 1, nullptr, S1);   // r  (xr->S1)
    k_gemm<<<1024, 256, 0, stream>>>(S2, WvT, 1, nullptr, S0);   // v  (xv->S0)
    k_gemm<<<1024, 256, 0, stream>>>(S4, WvT, 1, nullptr, S2);   // v2 (xv2->S2)
    // ---- merged K=64 epilogues: decay (fp32 into D) + v2 += lora ----
    k_gemm64<<<2048, 256, 0, stream>>>(Gd, dw2t, Gv, vw2t, decay, tdec, S2);
    // ---- chunked WKV scan (k~ = k*(1-d) inline; adds v2 in-place in S2) ----
    k_scan_chunked<<<128, 256, 0, stream>>>(S1, S3, S0, decay, wkvin, S2, out_state);
    // ---- LayerNorm (in-place) + output projection ----
    k_addln<<<M_ROWS, 256, 0, stream>>>(S2, lnw, lnb);
    k_gemm<<<1024, 256, 0, stream>>>(S2, WoT, 0, out_y, nullptr);

    (void)in_sizes; (void)n_in; (void)out_size;
}